// Round 12
// baseline (11245.889 us; speedup 1.0000x reference)
//
#include <hip/hip_runtime.h>
#include <cstdint>
#include <cstddef>

// ---------------------------------------------------------------------------
// FlowNet3D-style encoder/decoder pyramid (GenFlow_unit_mask).
// Round-12: fps level-1 DISTRIBUTED across 4 CUs per batch (global slot
// publish/poll per iteration, exact argmax semantics). Rest = round-11
// (fused dim-templated convs, two-stream fork-join, round-5 fps2/3/4).
// ---------------------------------------------------------------------------

static __device__ __forceinline__ float sq3_rn(float x, float y, float z) {
    // ((x*x + y*y) + z*z) strict IEEE (no fma) to bit-match numpy
    return __fadd_rn(__fadd_rn(__fmul_rn(x, x), __fmul_rn(y, y)), __fmul_rn(z, z));
}

// monotone float -> uint map (handles negatives from catastrophic cancellation)
static __device__ __forceinline__ unsigned int ford(float f) {
    unsigned int u = __float_as_uint(f);
    return u ^ ((u >> 31) ? 0xFFFFFFFFu : 0x80000000u);
}

// ---------------------------------------------------------------------------
// Branchless DPP wave-64 u32 reductions. Result lands in lane 63.
// bound_ctrl=false -> invalid-source lanes keep old value (identity).
// ---------------------------------------------------------------------------
template <int CTRL>
static __device__ __forceinline__ void dpp_umax_step(unsigned& v) {
    unsigned t = (unsigned)__builtin_amdgcn_update_dpp((int)v, (int)v, CTRL, 0xf, 0xf, false);
    v = (t > v) ? t : v;   // v_max_u32
}
template <int CTRL>
static __device__ __forceinline__ void dpp_umin_step(unsigned& v) {
    unsigned t = (unsigned)__builtin_amdgcn_update_dpp((int)v, (int)v, CTRL, 0xf, 0xf, false);
    v = (t < v) ? t : v;   // v_min_u32
}
static __device__ __forceinline__ unsigned dpp_wave_umax(unsigned v) {
    dpp_umax_step<0x111>(v);  // row_shr:1
    dpp_umax_step<0x112>(v);  // row_shr:2
    dpp_umax_step<0x114>(v);  // row_shr:4
    dpp_umax_step<0x118>(v);  // row_shr:8
    dpp_umax_step<0x142>(v);  // row_bcast:15
    dpp_umax_step<0x143>(v);  // row_bcast:31
    return v;                 // full max in lane 63
}
static __device__ __forceinline__ unsigned dpp_wave_umin(unsigned v) {
    dpp_umin_step<0x111>(v);
    dpp_umin_step<0x112>(v);
    dpp_umin_step<0x114>(v);
    dpp_umin_step<0x118>(v);
    dpp_umin_step<0x142>(v);
    dpp_umin_step<0x143>(v);
    return v;
}
static __device__ __forceinline__ void wave_argmin_u32pair(unsigned hi, unsigned lo,
                                                          unsigned& whi, unsigned& wlo) {
    unsigned h = dpp_wave_umin(hi);
    whi = (unsigned)__builtin_amdgcn_readlane((int)h, 63);
    unsigned cand = (hi == whi) ? lo : 0xFFFFFFFFu; // real lo (index) < 2^31
    unsigned l = dpp_wave_umin(cand);
    wlo = (unsigned)__builtin_amdgcn_readlane((int)l, 63);
}

// ---------------------------------------------------------------------------
// DISTRIBUTED FPS level-1. B*KBLK blocks; block (b,k) owns points
// [k*NB, (k+1)*NB) of batch b. Per iteration each WAVE publishes its local
// winner {seq=m+1, hi, global_bp, winner_xyz} to a 32B global slot
// (parity-double-buffered), then acquire-polls all GW slots and merges
// in-register (lanes 0..GW-1). Winner coords travel in the payload, so each
// block only mirrors its own range. Merge = max hi, then min global_bp =
// exact numpy first-occurrence. seq full-counter + parity kills staleness;
// release/acquire bounds wave skew to 1 iter (no same-parity overwrite race).
// Slots zeroed per launch via hipMemsetAsync (seq>=1 -> no garbage hits).
// All 8 blocks co-resident (<= 256 CUs) -> spin cannot deadlock.
// Dynamic LDS = NB*3*4 (own mirror) + M*4*4 (sout, block k==0 writes).
// ---------------------------------------------------------------------------
template <int T, int PB, int KBLK>
__global__ __launch_bounds__(T) __attribute__((amdgpu_waves_per_eu(1, 1)))
void fps_dist(const float* __restrict__ xyz, int M,
              float* __restrict__ new_xyz, float* __restrict__ out_idx,
              unsigned* __restrict__ gsl)
{
    static_assert(PB % 4 == 0, "PB must be a multiple of 4");
    constexpr int NW = T / 64;          // waves per block
    constexpr int GW = KBLK * NW;       // waves per batch (slots)
    constexpr int NB = T * PB;          // points per block
    constexpr int Q = PB / 4;
    const int blk = blockIdx.x;
    const int b = blk / KBLK, k = blk % KBLK;
    const int t = threadIdx.x;
    const int lane = t & 63, wave = t >> 6;
    const int gw = k * NW + wave;       // slot id within batch

    extern __shared__ float sm[];
    float* spts = sm;            // NB*3 own-range mirror
    float* sout = sm + NB * 3;   // M*4 (only block k==0 writes)

    const int N = KBLK * NB;
    const float* x0 = xyz + (size_t)b * N * 3;
    const float* xb = x0 + (size_t)k * NB * 3;
    for (int i = t; i < NB * 3; i += T) spts[i] = xb[i];

    float px[PB], py[PB], pz[PB], dist[PB];
#pragma unroll
    for (int j = 0; j < PB; ++j) {
        int p = t * PB + j;             // block-local thread-major
        px[j] = xb[p * 3 + 0];
        py[j] = xb[p * 3 + 1];
        pz[j] = xb[p * 3 + 2];
        dist[j] = 1e10f;
    }
    __syncthreads();

    unsigned* slt = gsl + (size_t)b * (2 * GW * 8);

    // initial centroid = point 0 (global), known to all blocks
    float cx = x0[0], cy = x0[1], cz = x0[2];
    int far = 0;

    for (int m = 0; m < M; ++m) {
        if (k == 0 && wave == 0 && lane == 0) {
            float* so = sout + m * 4;
            so[0] = cx; so[1] = cy; so[2] = cz; so[3] = (float)far;
        }
        // 4 independent quarter-scans (lower quarter = smaller local index)
        float bv[4]; int bj[4];
#pragma unroll
        for (int a = 0; a < 4; ++a) { bv[a] = -1.0f; bj[a] = 0; }
#pragma unroll
        for (int j = 0; j < Q; ++j) {
#pragma unroll
            for (int a = 0; a < 4; ++a) {
                int idx = a * Q + j;
                float dx = __fsub_rn(px[idx], cx);
                float dy = __fsub_rn(py[idx], cy);
                float dz = __fsub_rn(pz[idx], cz);
                float d  = sq3_rn(dx, dy, dz);
                float nd = fminf(dist[idx], d);
                dist[idx] = nd;
                bj[a] = (nd > bv[a]) ? idx : bj[a];   // strict >: first occurrence
                bv[a] = fmaxf(bv[a], nd);
            }
        }
        float bvv = bv[0]; int bjj = bj[0];
#pragma unroll
        for (int a = 1; a < 4; ++a) {
            bjj = (bv[a] > bvv) ? bj[a] : bjj;        // tie keeps lower quarter
            bvv = fmaxf(bvv, bv[a]);
        }
        // wave-local winner (min lane = min local index under thread-major)
        unsigned hi = __float_as_uint(bvv);           // bvv >= 0 -> monotone
        unsigned h = dpp_wave_umax(hi);
        unsigned whi = (unsigned)__builtin_amdgcn_readlane((int)h, 63);
        unsigned long long mk = __ballot(hi == whi);
        int L = (int)__builtin_ctzll(mk);
        int bjL = __builtin_amdgcn_readlane(bjj, L);
        int lbp = ((wave << 6) + L) * PB + bjL;       // block-local index
        unsigned gbp = (unsigned)(k * NB + lbp);      // global index

        // publish: payload then seq (release, agent scope)
        unsigned* my = slt + (((m & 1) * GW + gw) << 3);
        if (lane == 0) {
            my[1] = whi;
            my[2] = gbp;
            my[3] = __float_as_uint(spts[lbp * 3 + 0]);
            my[4] = __float_as_uint(spts[lbp * 3 + 1]);
            my[5] = __float_as_uint(spts[lbp * 3 + 2]);
            __hip_atomic_store(&my[0], (unsigned)(m + 1),
                               __ATOMIC_RELEASE, __HIP_MEMORY_SCOPE_AGENT);
        }

        // poll all GW slots (lane l < GW watches slot l)
        const bool act = lane < GW;
        unsigned* rs = slt + (((m & 1) * GW + (lane & (GW - 1))) << 3);
        for (;;) {
            unsigned sq = __hip_atomic_load(&rs[0], __ATOMIC_ACQUIRE,
                                            __HIP_MEMORY_SCOPE_AGENT);
            unsigned long long ok = __ballot(!act || sq == (unsigned)(m + 1));
            if (ok == ~0ull) break;
            __builtin_amdgcn_s_sleep(1);
        }
        unsigned shi = act ? rs[1] : 0u;
        unsigned sbp = act ? rs[2] : 0xFFFFFFFFu;
        float scx = __uint_as_float(rs[3]);
        float scy = __uint_as_float(rs[4]);
        float scz = __uint_as_float(rs[5]);

        // merge across slots: max hi, then min global bp (exact tie-break)
        unsigned h2 = dpp_wave_umax(shi);
        unsigned whi2 = (unsigned)__builtin_amdgcn_readlane((int)h2, 63);
        unsigned cand = (shi == whi2) ? sbp : 0xFFFFFFFFu;
        unsigned l2 = dpp_wave_umin(cand);
        unsigned wbp2 = (unsigned)__builtin_amdgcn_readlane((int)l2, 63);
        unsigned long long wm = __ballot(act && shi == whi2 && sbp == wbp2);
        int wl = (int)__builtin_ctzll(wm);
        cx = __uint_as_float(__builtin_amdgcn_readlane((int)__float_as_uint(scx), wl));
        cy = __uint_as_float(__builtin_amdgcn_readlane((int)__float_as_uint(scy), wl));
        cz = __uint_as_float(__builtin_amdgcn_readlane((int)__float_as_uint(scz), wl));
        far = (int)wbp2;
    }

    // block 0 flushes accumulated outputs
    if (k == 0) {
        __syncthreads();
        for (int i = t; i < M * 3; i += T) {
            int mm = i / 3, c = i - mm * 3;
            new_xyz[(size_t)b * M * 3 + i] = sout[mm * 4 + c];
        }
        if (out_idx) {
            for (int i = t; i < M; i += T)
                out_idx[(size_t)b * M + i] = sout[i * 4 + 3];
        }
    }
}

// ---------------------------------------------------------------------------
// FPS, multi-wave single-CU version (round-5; used for level 2).
// ---------------------------------------------------------------------------
template <int T, int P>
__global__ __launch_bounds__(T) __attribute__((amdgpu_waves_per_eu(1, 1)))
void fps_block(const float* __restrict__ xyz, int M,
               float* __restrict__ new_xyz, float* __restrict__ out_idx)
{
    static_assert(P % 4 == 0, "P must be a multiple of 4");
    constexpr int N = T * P;
    constexpr int NW = T / 64;
    constexpr int Q = P / 4;
    const int b = blockIdx.x;
    const int t = threadIdx.x;
    const int lane = t & 63, wave = t >> 6;

    __shared__ uint2 s_slot[2][NW];   // {hi, bp} per wave, parity-buffered
    extern __shared__ float sm[];
    float* spts = sm;           // N*3 point mirror
    float* sout = sm + N * 3;   // M*4: cx,cy,cz,(float)idx

    const float* x0 = xyz + (size_t)b * N * 3;
    for (int i = t; i < N * 3; i += T) spts[i] = x0[i];

    float px[P], py[P], pz[P], dist[P];
#pragma unroll
    for (int j = 0; j < P; ++j) {
        int p = t * P + j;          // thread-major
        px[j] = x0[p * 3 + 0];
        py[j] = x0[p * 3 + 1];
        pz[j] = x0[p * 3 + 2];
        dist[j] = 1e10f;
    }
    __syncthreads();

    int far = 0;
    for (int m = 0; m < M; ++m) {
        float cx = spts[far * 3 + 0];
        float cy = spts[far * 3 + 1];
        float cz = spts[far * 3 + 2];
        if (t == 0) {
            float* so = sout + m * 4;
            so[0] = cx; so[1] = cy; so[2] = cz; so[3] = (float)far;
        }
        float bv[4]; int bj[4];
#pragma unroll
        for (int a = 0; a < 4; ++a) { bv[a] = -1.0f; bj[a] = 0; }
#pragma unroll
        for (int j = 0; j < Q; ++j) {
#pragma unroll
            for (int a = 0; a < 4; ++a) {
                int idx = a * Q + j;
                float dx = __fsub_rn(px[idx], cx);
                float dy = __fsub_rn(py[idx], cy);
                float dz = __fsub_rn(pz[idx], cz);
                float d  = sq3_rn(dx, dy, dz);
                float nd = fminf(dist[idx], d);
                dist[idx] = nd;
                bj[a] = (nd > bv[a]) ? idx : bj[a];   // strict >: first occurrence
                bv[a] = fmaxf(bv[a], nd);
            }
        }
        float bvv = bv[0]; int bjj = bj[0];
#pragma unroll
        for (int a = 1; a < 4; ++a) {
            bjj = (bv[a] > bvv) ? bj[a] : bjj;        // tie keeps lower quarter
            bvv = fmaxf(bvv, bv[a]);
        }
        unsigned hi = __float_as_uint(bvv);
        unsigned h = dpp_wave_umax(hi);
        unsigned whi = (unsigned)__builtin_amdgcn_readlane((int)h, 63);
        unsigned long long mk = __ballot(hi == whi);
        int L = (int)__builtin_ctzll(mk);
        int bjL = __builtin_amdgcn_readlane(bjj, L);
        unsigned wbp = (unsigned)((((wave << 6) + L) * P) + bjL);
        if (lane == 0) s_slot[m & 1][wave] = make_uint2(whi, wbp);
        __syncthreads();
        uint2 sv[NW];
#pragma unroll
        for (int w2 = 0; w2 < NW; ++w2) sv[w2] = s_slot[m & 1][w2];
        unsigned bhi = 0u;
#pragma unroll
        for (int w2 = 0; w2 < NW; ++w2) bhi = (sv[w2].x > bhi) ? sv[w2].x : bhi;
        unsigned blo = 0xFFFFFFFFu;
#pragma unroll
        for (int w2 = 0; w2 < NW; ++w2) {
            unsigned c = (sv[w2].x == bhi) ? sv[w2].y : 0xFFFFFFFFu;
            blo = (c < blo) ? c : blo;                // wave ranges disjoint+ordered
        }
        far = (int)blo;
    }

    __syncthreads();
    for (int i = t; i < M * 3; i += T) {
        int mm = i / 3, c = i - mm * 3;
        new_xyz[(size_t)b * M * 3 + i] = sout[mm * 4 + c];
    }
    if (out_idx) {
        for (int i = t; i < M; i += T)
            out_idx[(size_t)b * M + i] = sout[i * 4 + 3];
    }
}

// ---------------------------------------------------------------------------
// FPS, single-wave version (round-5): thread-major, split accumulators,
// single-phase DPP + ballot. Dynamic LDS = N*3*4 + M*4*4.
// ---------------------------------------------------------------------------
template <int P>
__global__ __launch_bounds__(64) __attribute__((amdgpu_waves_per_eu(1, 1)))
void fps_wave(const float* __restrict__ xyz, int M,
              float* __restrict__ new_xyz, float* __restrict__ out_idx)
{
    constexpr int NA = (P % 4 == 0) ? 4 : 2;
    constexpr int Q = P / NA;
    const int b = blockIdx.x;
    const int lane = threadIdx.x;
    const int N = 64 * P;
    extern __shared__ float sm[];
    float* spts = sm;           // N*3
    float* sout = sm + N * 3;   // M*4
    const float* x0 = xyz + (size_t)b * N * 3;

    for (int i = lane; i < N * 3; i += 64) spts[i] = x0[i];

    float px[P], py[P], pz[P], dist[P];
#pragma unroll
    for (int j = 0; j < P; ++j) {
        int p = lane * P + j;       // thread-major
        px[j] = x0[p * 3 + 0];
        py[j] = x0[p * 3 + 1];
        pz[j] = x0[p * 3 + 2];
        dist[j] = 1e10f;
    }
    __syncthreads();

    int far = 0;
    for (int m = 0; m < M; ++m) {
        float cx = spts[far * 3 + 0];
        float cy = spts[far * 3 + 1];
        float cz = spts[far * 3 + 2];
        if (lane == 0) {
            float* so = sout + m * 4;
            so[0] = cx; so[1] = cy; so[2] = cz; so[3] = (float)far;
        }
        float bv[NA]; int bj[NA];
#pragma unroll
        for (int a = 0; a < NA; ++a) { bv[a] = -1.0f; bj[a] = 0; }
#pragma unroll
        for (int j = 0; j < Q; ++j) {
#pragma unroll
            for (int a = 0; a < NA; ++a) {
                int idx = a * Q + j;
                float dx = __fsub_rn(px[idx], cx);
                float dy = __fsub_rn(py[idx], cy);
                float dz = __fsub_rn(pz[idx], cz);
                float d  = sq3_rn(dx, dy, dz);
                float nd = fminf(dist[idx], d);
                dist[idx] = nd;
                bj[a] = (nd > bv[a]) ? idx : bj[a];
                bv[a] = fmaxf(bv[a], nd);
            }
        }
        float bvv = bv[0]; int bjj = bj[0];
#pragma unroll
        for (int a = 1; a < NA; ++a) {
            bjj = (bv[a] > bvv) ? bj[a] : bjj;
            bvv = fmaxf(bvv, bv[a]);
        }
        unsigned hi = __float_as_uint(bvv);
        unsigned h = dpp_wave_umax(hi);
        unsigned whi = (unsigned)__builtin_amdgcn_readlane((int)h, 63);
        unsigned long long mk = __ballot(hi == whi);
        int L = (int)__builtin_ctzll(mk);
        int bjL = __builtin_amdgcn_readlane(bjj, L);
        far = L * P + bjL;
    }

    __syncthreads();
    for (int i = lane; i < M * 3; i += 64) {
        int mm = i / 3, c = i - mm * 3;
        new_xyz[(size_t)b * M * 3 + i] = sout[mm * 4 + c];
    }
    if (out_idx) {
        for (int i = lane; i < M; i += 64)
            out_idx[(size_t)b * M + i] = sout[i * 4 + 3];
    }
}

// ---------------------------------------------------------------------------
// FUSED KNN + SetConv, ALL dims compile-time (round-10 verified).
// ---------------------------------------------------------------------------
template <int K, int Cin, int C1, int C2>
__global__ __launch_bounds__(256)
void setconv_full(const float* __restrict__ ref_xyz, int N,
                  const float* __restrict__ ref_feat,
                  const float* __restrict__ new_xyz, int M,
                  const float* __restrict__ W0, const float* __restrict__ b0,
                  const float* __restrict__ W1, const float* __restrict__ b1,
                  float* __restrict__ out)
{
    constexpr int Cin3 = Cin + 3;
    const int b = blockIdx.y;
    const int tid = threadIdx.x;
    const int lane = tid & 63, ty = tid >> 6;
    const int m = blockIdx.x * 4 + ty;

    extern __shared__ float sm[];
    int*   nidx_s = (int*)sm;                 // [4][K]
    float* hb  = sm + 4 * K;                  // [4][K*Cin3]
    float* h1b = hb + 4 * K * Cin3;           // [4][K*C1]
    float* h  = hb  + ty * K * Cin3;
    float* h1 = h1b + ty * K * C1;

    const size_t qg = (size_t)b * M + m;
    const float* qp = new_xyz + qg * 3;
    const float qx = qp[0], qy = qp[1], qz = qp[2];

    {
        const float sq = sq3_rn(qx, qy, qz);
        float dk[K]; int ik[K];
#pragma unroll
        for (int j = 0; j < K; ++j) { dk[j] = INFINITY; ik[j] = 0x7fffffff; }
        const float* rb = ref_xyz + (size_t)b * N * 3;
        for (int n = lane; n < N; n += 64) {
            const float* rp = rb + (size_t)n * 3;
            float rx = rp[0], ry = rp[1], rz = rp[2];
            float sr = sq3_rn(rx, ry, rz);
            float dot = __fadd_rn(__fadd_rn(__fmul_rn(qx, rx), __fmul_rn(qy, ry)),
                                  __fmul_rn(qz, rz));
            float d = __fadd_rn(__fsub_rn(sq, __fmul_rn(2.0f, dot)), sr);
            if (d < dk[K - 1]) {
                dk[K - 1] = d;
                ik[K - 1] = n;
#pragma unroll
                for (int j = K - 1; j > 0; --j) {
                    if (dk[j] < dk[j - 1]) {
                        float tv = dk[j]; dk[j] = dk[j - 1]; dk[j - 1] = tv;
                        int   ti = ik[j]; ik[j] = ik[j - 1]; ik[j - 1] = ti;
                    }
                }
            }
        }
        unsigned hiA[K], loA[K];
#pragma unroll
        for (int j = 0; j < K; ++j) { hiA[j] = ford(dk[j]); loA[j] = (unsigned)ik[j]; }
        int winner = 0;
        for (int r = 0; r < K; ++r) {
            unsigned bhi, blo;
            wave_argmin_u32pair(hiA[0], loA[0], bhi, blo);
            if (lane == r) winner = (int)blo;
            if (hiA[0] == bhi && loA[0] == blo) {
#pragma unroll
                for (int j = 0; j < K - 1; ++j) { hiA[j] = hiA[j + 1]; loA[j] = loA[j + 1]; }
                hiA[K - 1] = 0xFFFFFFFFu;
                loA[K - 1] = 0xFFFFFFFFu;
            }
        }
        if (lane < K) nidx_s[ty * K + lane] = winner;
    }
    __syncthreads();

    for (int j = 0; j < K; ++j) {
        int n = nidx_s[ty * K + j];
        const float* xp = ref_xyz + ((size_t)b * N + n) * 3;
        const float* fp = ref_feat + ((size_t)b * N + n) * Cin;
        for (int i = lane; i < Cin3; i += 64) {
            float v;
            if (i == 0)      v = __fsub_rn(xp[0], qx);
            else if (i == 1) v = __fsub_rn(xp[1], qy);
            else if (i == 2) v = __fsub_rn(xp[2], qz);
            else             v = fp[i - 3];
            h[j * Cin3 + i] = v;
        }
    }
    __syncthreads();

#pragma unroll
    for (int c0 = 0; c0 < C1; c0 += 64) {
        int c = c0 + lane;
        bool act = c < C1;
        float acc[K];
        float bias = act ? b0[c] : 0.0f;
#pragma unroll
        for (int j = 0; j < K; ++j) acc[j] = bias;
        for (int i = 0; i < Cin3; ++i) {
            float w = act ? W0[i * C1 + c] : 0.0f;
#pragma unroll
            for (int j = 0; j < K; ++j) acc[j] = fmaf(h[j * Cin3 + i], w, acc[j]);
        }
        if (act) {
#pragma unroll
            for (int j = 0; j < K; ++j) h1[j * C1 + c] = fmaxf(acc[j], 0.0f);
        }
    }
    __syncthreads();

#pragma unroll
    for (int c0 = 0; c0 < C2; c0 += 64) {
        int c = c0 + lane;
        bool act = c < C2;
        float acc[K];
        float bias = act ? b1[c] : 0.0f;
#pragma unroll
        for (int j = 0; j < K; ++j) acc[j] = bias;
        for (int i = 0; i < C1; ++i) {
            float w = act ? W1[i * C2 + c] : 0.0f;
#pragma unroll
            for (int j = 0; j < K; ++j) acc[j] = fmaf(h1[j * C1 + i], w, acc[j]);
        }
        if (act) {
            float mv = acc[0];
#pragma unroll
            for (int j = 1; j < K; ++j) mv = fmaxf(mv, acc[j]);
            out[qg * C2 + c] = fmaxf(mv, 0.0f);
        }
    }
}

// ---------------------------------------------------------------------------
// FUSED KNN + SetUpConv, ALL dims compile-time (round-10 verified).
// ---------------------------------------------------------------------------
template <int K, int Cc, int Cf, int C1, int C2>
__global__ __launch_bounds__(256)
void upconv_full(const float* __restrict__ cxyz, int Nc,
                 const float* __restrict__ cf,
                 const float* __restrict__ fxyz, int M,
                 const float* __restrict__ ff,
                 const float* __restrict__ W1, const float* __restrict__ b1,
                 const float* __restrict__ W2, const float* __restrict__ b2,
                 float* __restrict__ out)
{
    constexpr int Cc3 = Cc + 3;
    const int b = blockIdx.y;
    const int tid = threadIdx.x;
    const int lane = tid & 63, ty = tid >> 6;
    const int m = blockIdx.x * 4 + ty;

    extern __shared__ float sm[];
    int*   nidx_s = (int*)sm;                 // [4][K]
    float* hb = sm + 4 * K;                   // [4][K*Cc3]
    float* gb = hb + 4 * K * Cc3;             // [4][C1+Cf]
    float* h = hb + ty * K * Cc3;
    float* g = gb + ty * (C1 + Cf);

    const size_t qg = (size_t)b * M + m;
    const float* qp = fxyz + qg * 3;
    const float qx = qp[0], qy = qp[1], qz = qp[2];

    {
        const float sq = sq3_rn(qx, qy, qz);
        float dk[K]; int ik[K];
#pragma unroll
        for (int j = 0; j < K; ++j) { dk[j] = INFINITY; ik[j] = 0x7fffffff; }
        const float* rb = cxyz + (size_t)b * Nc * 3;
        for (int n = lane; n < Nc; n += 64) {
            const float* rp = rb + (size_t)n * 3;
            float rx = rp[0], ry = rp[1], rz = rp[2];
            float sr = sq3_rn(rx, ry, rz);
            float dot = __fadd_rn(__fadd_rn(__fmul_rn(qx, rx), __fmul_rn(qy, ry)),
                                  __fmul_rn(qz, rz));
            float d = __fadd_rn(__fsub_rn(sq, __fmul_rn(2.0f, dot)), sr);
            if (d < dk[K - 1]) {
                dk[K - 1] = d;
                ik[K - 1] = n;
#pragma unroll
                for (int j = K - 1; j > 0; --j) {
                    if (dk[j] < dk[j - 1]) {
                        float tv = dk[j]; dk[j] = dk[j - 1]; dk[j - 1] = tv;
                        int   ti = ik[j]; ik[j] = ik[j - 1]; ik[j - 1] = ti;
                    }
                }
            }
        }
        unsigned hiA[K], loA[K];
#pragma unroll
        for (int j = 0; j < K; ++j) { hiA[j] = ford(dk[j]); loA[j] = (unsigned)ik[j]; }
        int winner = 0;
        for (int r = 0; r < K; ++r) {
            unsigned bhi, blo;
            wave_argmin_u32pair(hiA[0], loA[0], bhi, blo);
            if (lane == r) winner = (int)blo;
            if (hiA[0] == bhi && loA[0] == blo) {
#pragma unroll
                for (int j = 0; j < K - 1; ++j) { hiA[j] = hiA[j + 1]; loA[j] = loA[j + 1]; }
                hiA[K - 1] = 0xFFFFFFFFu;
                loA[K - 1] = 0xFFFFFFFFu;
            }
        }
        if (lane < K) nidx_s[ty * K + lane] = winner;
    }
    __syncthreads();

    for (int j = 0; j < K; ++j) {
        int n = nidx_s[ty * K + j];
        const float* xp = cxyz + ((size_t)b * Nc + n) * 3;
        const float* fp = cf + ((size_t)b * Nc + n) * Cc;
        for (int i = lane; i < Cc3; i += 64) {
            float v;
            if (i == 0)      v = __fsub_rn(xp[0], qx);
            else if (i == 1) v = __fsub_rn(xp[1], qy);
            else if (i == 2) v = __fsub_rn(xp[2], qz);
            else             v = fp[i - 3];
            h[j * Cc3 + i] = v;
        }
    }
    for (int i = lane; i < Cf; i += 64) g[C1 + i] = ff[qg * Cf + i];
    __syncthreads();

#pragma unroll
    for (int c0 = 0; c0 < C1; c0 += 64) {
        int c = c0 + lane;
        bool act = c < C1;
        float acc[K];
        float bias = act ? b1[c] : 0.0f;
#pragma unroll
        for (int j = 0; j < K; ++j) acc[j] = bias;
        for (int i = 0; i < Cc3; ++i) {
            float w = act ? W1[i * C1 + c] : 0.0f;
#pragma unroll
            for (int j = 0; j < K; ++j) acc[j] = fmaf(h[j * Cc3 + i], w, acc[j]);
        }
        if (act) {
            float mv = acc[0];
#pragma unroll
            for (int j = 1; j < K; ++j) mv = fmaxf(mv, acc[j]);
            g[c] = fmaxf(mv, 0.0f);
        }
    }
    __syncthreads();

    constexpr int Cg = C1 + Cf;
#pragma unroll
    for (int c0 = 0; c0 < C2; c0 += 64) {
        int c = c0 + lane;
        bool act = c < C2;
        float acc = act ? b2[c] : 0.0f;
        for (int i = 0; i < Cg; ++i) {
            float w = act ? W2[i * C2 + c] : 0.0f;
            acc = fmaf(g[i], w, acc);
        }
        if (act) out[qg * C2 + c] = fmaxf(acc, 0.0f);
    }
}

// ---------------------------------------------------------------------------
// f0 = relu(feat @ d0_W + d0_b), 3 -> 32 channels.
// ---------------------------------------------------------------------------
__global__ void f0_kernel(const float* __restrict__ feat, const float* __restrict__ W,
                          const float* __restrict__ bias, float* __restrict__ out)
{
    int t = blockIdx.x * blockDim.x + threadIdx.x;
    int n = t >> 5, c = t & 31;
    const float* f = feat + (size_t)n * 3;
    float acc = bias[c];
    acc = fmaf(f[0], W[c], acc);
    acc = fmaf(f[1], W[32 + c], acc);
    acc = fmaf(f[2], W[64 + c], acc);
    out[t] = fmaxf(acc, 0.0f);
}

// ---------------------------------------------------------------------------

extern "C" void kernel_launch(void* const* d_in, const int* in_sizes, int n_in,
                              void* d_out, int out_size, void* d_ws, size_t ws_size,
                              hipStream_t stream)
{
    const float* pc    = (const float*)d_in[0];
    const float* feat  = (const float*)d_in[1];
    const float* d0_W  = (const float*)d_in[2];
    const float* d0_b  = (const float*)d_in[3];
    const float* d1_W0 = (const float*)d_in[4];
    const float* d1_b0 = (const float*)d_in[5];
    const float* d1_W1 = (const float*)d_in[6];
    const float* d1_b1 = (const float*)d_in[7];
    const float* d2_W0 = (const float*)d_in[8];
    const float* d2_b0 = (const float*)d_in[9];
    const float* d2_W1 = (const float*)d_in[10];
    const float* d2_b1 = (const float*)d_in[11];
    const float* d3_W0 = (const float*)d_in[12];
    const float* d3_b0 = (const float*)d_in[13];
    const float* d3_W1 = (const float*)d_in[14];
    const float* d3_b1 = (const float*)d_in[15];
    const float* d4_W0 = (const float*)d_in[16];
    const float* d4_b0 = (const float*)d_in[17];
    const float* d4_W1 = (const float*)d_in[18];
    const float* d4_b1 = (const float*)d_in[19];
    const float* u4_W1 = (const float*)d_in[20];
    const float* u4_b1 = (const float*)d_in[21];
    const float* u4_W2 = (const float*)d_in[22];
    const float* u4_b2 = (const float*)d_in[23];
    const float* u3_W1 = (const float*)d_in[24];
    const float* u3_b1 = (const float*)d_in[25];
    const float* u3_W2 = (const float*)d_in[26];
    const float* u3_b2 = (const float*)d_in[27];
    const float* u2_W1 = (const float*)d_in[28];
    const float* u2_b1 = (const float*)d_in[29];
    const float* u2_W2 = (const float*)d_in[30];
    const float* u2_b2 = (const float*)d_in[31];
    const float* u1_W1 = (const float*)d_in[32];
    const float* u1_b1 = (const float*)d_in[33];
    const float* u1_W2 = (const float*)d_in[34];
    const float* u1_b2 = (const float*)d_in[35];

    float* out = (float*)d_out;
    float* o_x1 = out + 0;       // 12288
    float* o_x2 = out + 12288;   // 3072
    float* o_x3 = out + 15360;   // 768
    float* o_i1 = out + 16128;   // 4096
    float* o_i2 = out + 20224;   // 1024
    float* o_i3 = out + 21248;   // 256
    float* o_u0 = out + 21504;   // 524288
    float* o_u1 = out + 545792;  // 262144
    float* o_u2 = out + 807936;  // 131072
    float* o_u3 = out + 939008;  // 49152

    float* w = (float*)d_ws;
    float* f0 = w; w += 2 * 8192 * 32;
    float* f1 = w; w += 2 * 2048 * 64;
    float* f2 = w; w += 2 * 512 * 128;
    float* f3 = w; w += 2 * 128 * 192;
    float* f4 = w; w += 2 * 64 * 192;
    float* x4 = w; w += 2 * 64 * 3;
    unsigned* gsl = (unsigned*)w;    // 2 batches * 2 parity * 16 waves * 8 u32

    const int B = 2;
    const int GSL_BYTES = 2 * 2 * 16 * 8 * 4;   // 4096

    // one-time setup: LDS caps + second stream + fork/join events
    static bool init_done = false;
    static hipStream_t s2 = nullptr;
    static hipEvent_t evFork = nullptr, evX1 = nullptr, evX2 = nullptr,
                      evX3 = nullptr, evX4 = nullptr, evJoin = nullptr;
    if (!init_done) {
        (void)hipFuncSetAttribute((const void*)setconv_full<16, 128, 128, 192>,
                                  hipFuncAttributeMaxDynamicSharedMemorySize,
                                  (4 * 16 + 4 * 16 * 131 + 4 * 16 * 128) * 4); // 66560
        (void)hipFuncSetAttribute((const void*)setconv_full<16, 192, 192, 192>,
                                  hipFuncAttributeMaxDynamicSharedMemorySize,
                                  (4 * 16 + 4 * 16 * 195 + 4 * 16 * 192) * 4); // 99328
        (void)hipStreamCreateWithFlags(&s2, hipStreamNonBlocking);
        (void)hipEventCreateWithFlags(&evFork, hipEventDisableTiming);
        (void)hipEventCreateWithFlags(&evX1, hipEventDisableTiming);
        (void)hipEventCreateWithFlags(&evX2, hipEventDisableTiming);
        (void)hipEventCreateWithFlags(&evX3, hipEventDisableTiming);
        (void)hipEventCreateWithFlags(&evX4, hipEventDisableTiming);
        (void)hipEventCreateWithFlags(&evJoin, hipEventDisableTiming);
        init_done = true;
    }

    // zero the sync slots (capture-legal stream op), then fork
    (void)hipMemsetAsync(gsl, 0, GSL_BYTES, stream);
    (void)hipEventRecord(evFork, stream);
    (void)hipStreamWaitEvent(s2, evFork, 0);

    // f0 on s2, concurrent with fps1
    f0_kernel<<<(2 * 8192 * 32) / 256, 256, 0, s2>>>(feat, d0_W, d0_b, f0);

    // ---- fps chain on main stream (level 1 distributed over 4 CUs/batch) ----
    fps_dist<256, 8, 4><<<B * 4, 256, 2048 * 3 * 4 + 2048 * 4 * 4, stream>>>(
        pc, 2048, o_x1, o_i1, gsl);
    (void)hipEventRecord(evX1, stream);
    fps_block<256, 8><<<B, 256, 2048 * 3 * 4 + 512 * 4 * 4, stream>>>(o_x1, 512, o_x2, o_i2);
    (void)hipEventRecord(evX2, stream);
    fps_wave<8><<<B, 64, 512 * 3 * 4 + 128 * 4 * 4, stream>>>(o_x2, 128, o_x3, o_i3);
    (void)hipEventRecord(evX3, stream);
    fps_wave<2><<<B, 64, 128 * 3 * 4 + 64 * 4 * 4, stream>>>(o_x3, 64, x4, nullptr);
    (void)hipEventRecord(evX4, stream);

    // ---- feature chain on s2, gated on the fps outputs it needs ----
    (void)hipStreamWaitEvent(s2, evX1, 0);   // o_x1 ready
    setconv_full<16, 32, 32, 64><<<dim3(2048 / 4, B), 256,
        (4 * 16 + 4 * 16 * 35 + 4 * 16 * 32) * 4, s2>>>(
        pc, 8192, f0, o_x1, 2048, d1_W0, d1_b0, d1_W1, d1_b1, f1);
    (void)hipStreamWaitEvent(s2, evX2, 0);   // o_x2 ready
    setconv_full<16, 64, 64, 128><<<dim3(512 / 4, B), 256,
        (4 * 16 + 4 * 16 * 67 + 4 * 16 * 64) * 4, s2>>>(
        o_x1, 2048, f1, o_x2, 512, d2_W0, d2_b0, d2_W1, d2_b1, f2);
    (void)hipStreamWaitEvent(s2, evX3, 0);   // o_x3 ready
    setconv_full<16, 128, 128, 192><<<dim3(128 / 4, B), 256,
        (4 * 16 + 4 * 16 * 131 + 4 * 16 * 128) * 4, s2>>>(
        o_x2, 512, f2, o_x3, 128, d3_W0, d3_b0, d3_W1, d3_b1, f3);
    (void)hipStreamWaitEvent(s2, evX4, 0);   // x4 ready
    setconv_full<16, 192, 192, 192><<<dim3(64 / 4, B), 256,
        (4 * 16 + 4 * 16 * 195 + 4 * 16 * 192) * 4, s2>>>(
        o_x3, 128, f3, x4, 64, d4_W0, d4_b0, d4_W1, d4_b1, f4);

    upconv_full<8, 192, 192, 192, 192><<<dim3(128 / 4, B), 256,
        (4 * 8 + 4 * 8 * 195 + 4 * (192 + 192)) * 4, s2>>>(
        x4, 64, f4, o_x3, 128, f3, u4_W1, u4_b1, u4_W2, u4_b2, o_u3);
    upconv_full<8, 192, 128, 128, 128><<<dim3(512 / 4, B), 256,
        (4 * 8 + 4 * 8 * 195 + 4 * (128 + 128)) * 4, s2>>>(
        o_x3, 128, o_u3, o_x2, 512, f2, u3_W1, u3_b1, u3_W2, u3_b2, o_u2);
    upconv_full<8, 128, 64, 64, 64><<<dim3(2048 / 4, B), 256,
        (4 * 8 + 4 * 8 * 131 + 4 * (64 + 64)) * 4, s2>>>(
        o_x2, 512, o_u2, o_x1, 2048, f1, u2_W1, u2_b1, u2_W2, u2_b2, o_u1);
    upconv_full<8, 64, 32, 32, 32><<<dim3(8192 / 4, B), 256,
        (4 * 8 + 4 * 8 * 67 + 4 * (32 + 32)) * 4, s2>>>(
        o_x1, 2048, o_u1, pc, 8192, f0, u1_W1, u1_b1, u1_W2, u1_b2, o_u0);

    // ---- join: main stream waits for the feature chain ----
    (void)hipEventRecord(evJoin, s2);
    (void)hipStreamWaitEvent(stream, evJoin, 0);
}

// Round 13
// 2825.278 us; speedup vs baseline: 3.9805x; 3.9805x over previous
//
#include <hip/hip_runtime.h>
#include <cstdint>
#include <cstddef>

// ---------------------------------------------------------------------------
// FlowNet3D-style encoder/decoder pyramid (GenFlow_unit_mask).
// Round-13: round-11 base (2789us verified) + up-path KNNs split out and
// hoisted onto a third stream (each KNN depends only on coords, available
// much earlier than the serial u3->u2->u1->u0 conv chain consumes them).
// fps1 = round-5 single-CU floor (distributed variant measured 6x worse:
// cross-CU per-iter sync ~12400cy).
// ---------------------------------------------------------------------------

static __device__ __forceinline__ float sq3_rn(float x, float y, float z) {
    // ((x*x + y*y) + z*z) strict IEEE (no fma) to bit-match numpy
    return __fadd_rn(__fadd_rn(__fmul_rn(x, x), __fmul_rn(y, y)), __fmul_rn(z, z));
}

// monotone float -> uint map (handles negatives from catastrophic cancellation)
static __device__ __forceinline__ unsigned int ford(float f) {
    unsigned int u = __float_as_uint(f);
    return u ^ ((u >> 31) ? 0xFFFFFFFFu : 0x80000000u);
}

// ---------------------------------------------------------------------------
// Branchless DPP wave-64 u32 reductions. Result lands in lane 63.
// bound_ctrl=false -> invalid-source lanes keep old value (identity).
// ---------------------------------------------------------------------------
template <int CTRL>
static __device__ __forceinline__ void dpp_umax_step(unsigned& v) {
    unsigned t = (unsigned)__builtin_amdgcn_update_dpp((int)v, (int)v, CTRL, 0xf, 0xf, false);
    v = (t > v) ? t : v;   // v_max_u32
}
template <int CTRL>
static __device__ __forceinline__ void dpp_umin_step(unsigned& v) {
    unsigned t = (unsigned)__builtin_amdgcn_update_dpp((int)v, (int)v, CTRL, 0xf, 0xf, false);
    v = (t < v) ? t : v;   // v_min_u32
}
static __device__ __forceinline__ unsigned dpp_wave_umax(unsigned v) {
    dpp_umax_step<0x111>(v);  // row_shr:1
    dpp_umax_step<0x112>(v);  // row_shr:2
    dpp_umax_step<0x114>(v);  // row_shr:4
    dpp_umax_step<0x118>(v);  // row_shr:8
    dpp_umax_step<0x142>(v);  // row_bcast:15
    dpp_umax_step<0x143>(v);  // row_bcast:31
    return v;                 // full max in lane 63
}
static __device__ __forceinline__ unsigned dpp_wave_umin(unsigned v) {
    dpp_umin_step<0x111>(v);
    dpp_umin_step<0x112>(v);
    dpp_umin_step<0x114>(v);
    dpp_umin_step<0x118>(v);
    dpp_umin_step<0x142>(v);
    dpp_umin_step<0x143>(v);
    return v;
}
static __device__ __forceinline__ void wave_argmin_u32pair(unsigned hi, unsigned lo,
                                                          unsigned& whi, unsigned& wlo) {
    unsigned h = dpp_wave_umin(hi);
    whi = (unsigned)__builtin_amdgcn_readlane((int)h, 63);
    unsigned cand = (hi == whi) ? lo : 0xFFFFFFFFu; // real lo (index) < 2^31
    unsigned l = dpp_wave_umin(cand);
    wlo = (unsigned)__builtin_amdgcn_readlane((int)l, 63);
}

// ---------------------------------------------------------------------------
// FPS, multi-wave single-CU version (round-5 floor: ~1778us at L1).
// THREAD-MAJOR mapping; 4 split accumulators; single DPP phase + ballot
// (min lane = min point index, exact numpy first-occurrence); cross-wave
// merge via parity-buffered LDS slots; LDS-accumulated outputs.
// Dynamic LDS = N*3*4 (mirror) + M*4*4 (out).
// ---------------------------------------------------------------------------
template <int T, int P>
__global__ __launch_bounds__(T) __attribute__((amdgpu_waves_per_eu(1, 1)))
void fps_block(const float* __restrict__ xyz, int M,
               float* __restrict__ new_xyz, float* __restrict__ out_idx)
{
    static_assert(P % 4 == 0, "P must be a multiple of 4");
    constexpr int N = T * P;
    constexpr int NW = T / 64;
    constexpr int Q = P / 4;
    const int b = blockIdx.x;
    const int t = threadIdx.x;
    const int lane = t & 63, wave = t >> 6;

    __shared__ uint2 s_slot[2][NW];   // {hi, bp} per wave, parity-buffered
    extern __shared__ float sm[];
    float* spts = sm;           // N*3 point mirror
    float* sout = sm + N * 3;   // M*4: cx,cy,cz,(float)idx

    const float* x0 = xyz + (size_t)b * N * 3;
    for (int i = t; i < N * 3; i += T) spts[i] = x0[i];

    float px[P], py[P], pz[P], dist[P];
#pragma unroll
    for (int j = 0; j < P; ++j) {
        int p = t * P + j;          // thread-major
        px[j] = x0[p * 3 + 0];
        py[j] = x0[p * 3 + 1];
        pz[j] = x0[p * 3 + 2];
        dist[j] = 1e10f;
    }
    __syncthreads();

    int far = 0;
    for (int m = 0; m < M; ++m) {
        float cx = spts[far * 3 + 0];
        float cy = spts[far * 3 + 1];
        float cz = spts[far * 3 + 2];
        if (t == 0) {
            float* so = sout + m * 4;
            so[0] = cx; so[1] = cy; so[2] = cz; so[3] = (float)far;
        }
        float bv[4]; int bj[4];
#pragma unroll
        for (int a = 0; a < 4; ++a) { bv[a] = -1.0f; bj[a] = 0; }
#pragma unroll
        for (int j = 0; j < Q; ++j) {
#pragma unroll
            for (int a = 0; a < 4; ++a) {
                int idx = a * Q + j;
                float dx = __fsub_rn(px[idx], cx);
                float dy = __fsub_rn(py[idx], cy);
                float dz = __fsub_rn(pz[idx], cz);
                float d  = sq3_rn(dx, dy, dz);
                float nd = fminf(dist[idx], d);
                dist[idx] = nd;
                bj[a] = (nd > bv[a]) ? idx : bj[a];   // strict >: first occurrence
                bv[a] = fmaxf(bv[a], nd);
            }
        }
        float bvv = bv[0]; int bjj = bj[0];
#pragma unroll
        for (int a = 1; a < 4; ++a) {
            bjj = (bv[a] > bvv) ? bj[a] : bjj;        // tie keeps lower quarter
            bvv = fmaxf(bvv, bv[a]);
        }
        unsigned hi = __float_as_uint(bvv);           // bvv >= 0 -> monotone bits
        unsigned h = dpp_wave_umax(hi);
        unsigned whi = (unsigned)__builtin_amdgcn_readlane((int)h, 63);
        unsigned long long mk = __ballot(hi == whi);  // nonempty (max matches self)
        int L = (int)__builtin_ctzll(mk);             // min lane = min point idx
        int bjL = __builtin_amdgcn_readlane(bjj, L);
        unsigned wbp = (unsigned)((((wave << 6) + L) * P) + bjL);
        if (lane == 0) s_slot[m & 1][wave] = make_uint2(whi, wbp);
        __syncthreads();
        uint2 sv[NW];
#pragma unroll
        for (int w2 = 0; w2 < NW; ++w2) sv[w2] = s_slot[m & 1][w2];
        unsigned bhi = 0u;
#pragma unroll
        for (int w2 = 0; w2 < NW; ++w2) bhi = (sv[w2].x > bhi) ? sv[w2].x : bhi;
        unsigned blo = 0xFFFFFFFFu;
#pragma unroll
        for (int w2 = 0; w2 < NW; ++w2) {
            unsigned c = (sv[w2].x == bhi) ? sv[w2].y : 0xFFFFFFFFu;
            blo = (c < blo) ? c : blo;                // wave ranges disjoint+ordered
        }
        far = (int)blo;
    }

    __syncthreads();
    for (int i = t; i < M * 3; i += T) {
        int mm = i / 3, c = i - mm * 3;
        new_xyz[(size_t)b * M * 3 + i] = sout[mm * 4 + c];
    }
    if (out_idx) {
        for (int i = t; i < M; i += T)
            out_idx[(size_t)b * M + i] = sout[i * 4 + 3];
    }
}

// ---------------------------------------------------------------------------
// FPS, single-wave version (round-5). Dynamic LDS = N*3*4 + M*4*4.
// ---------------------------------------------------------------------------
template <int P>
__global__ __launch_bounds__(64) __attribute__((amdgpu_waves_per_eu(1, 1)))
void fps_wave(const float* __restrict__ xyz, int M,
              float* __restrict__ new_xyz, float* __restrict__ out_idx)
{
    constexpr int NA = (P % 4 == 0) ? 4 : 2;
    constexpr int Q = P / NA;
    const int b = blockIdx.x;
    const int lane = threadIdx.x;
    const int N = 64 * P;
    extern __shared__ float sm[];
    float* spts = sm;           // N*3
    float* sout = sm + N * 3;   // M*4
    const float* x0 = xyz + (size_t)b * N * 3;

    for (int i = lane; i < N * 3; i += 64) spts[i] = x0[i];

    float px[P], py[P], pz[P], dist[P];
#pragma unroll
    for (int j = 0; j < P; ++j) {
        int p = lane * P + j;       // thread-major
        px[j] = x0[p * 3 + 0];
        py[j] = x0[p * 3 + 1];
        pz[j] = x0[p * 3 + 2];
        dist[j] = 1e10f;
    }
    __syncthreads();

    int far = 0;
    for (int m = 0; m < M; ++m) {
        float cx = spts[far * 3 + 0];
        float cy = spts[far * 3 + 1];
        float cz = spts[far * 3 + 2];
        if (lane == 0) {
            float* so = sout + m * 4;
            so[0] = cx; so[1] = cy; so[2] = cz; so[3] = (float)far;
        }
        float bv[NA]; int bj[NA];
#pragma unroll
        for (int a = 0; a < NA; ++a) { bv[a] = -1.0f; bj[a] = 0; }
#pragma unroll
        for (int j = 0; j < Q; ++j) {
#pragma unroll
            for (int a = 0; a < NA; ++a) {
                int idx = a * Q + j;
                float dx = __fsub_rn(px[idx], cx);
                float dy = __fsub_rn(py[idx], cy);
                float dz = __fsub_rn(pz[idx], cz);
                float d  = sq3_rn(dx, dy, dz);
                float nd = fminf(dist[idx], d);
                dist[idx] = nd;
                bj[a] = (nd > bv[a]) ? idx : bj[a];
                bv[a] = fmaxf(bv[a], nd);
            }
        }
        float bvv = bv[0]; int bjj = bj[0];
#pragma unroll
        for (int a = 1; a < NA; ++a) {
            bjj = (bv[a] > bvv) ? bj[a] : bjj;
            bvv = fmaxf(bvv, bv[a]);
        }
        unsigned hi = __float_as_uint(bvv);
        unsigned h = dpp_wave_umax(hi);
        unsigned whi = (unsigned)__builtin_amdgcn_readlane((int)h, 63);
        unsigned long long mk = __ballot(hi == whi);
        int L = (int)__builtin_ctzll(mk);
        int bjL = __builtin_amdgcn_readlane(bjj, L);
        far = L * P + bjL;
    }

    __syncthreads();
    for (int i = lane; i < M * 3; i += 64) {
        int mm = i / 3, c = i - mm * 3;
        new_xyz[(size_t)b * M * 3 + i] = sout[mm * 4 + c];
    }
    if (out_idx) {
        for (int i = lane; i < M; i += 64)
            out_idx[(size_t)b * M + i] = sout[i * 4 + 3];
    }
}

// ---------------------------------------------------------------------------
// KNN, one WAVE per query (round-8 proven). Writes nidx to global.
// ---------------------------------------------------------------------------
#define KNN_QPB 4
template <int K>
__global__ void knn_wave(const float* __restrict__ query, int M,
                         const float* __restrict__ ref, int N,
                         int* __restrict__ nidx)
{
    const int b = blockIdx.y;
    const int m = blockIdx.x * KNN_QPB + threadIdx.y;
    const int lane = threadIdx.x;
    if (m >= M) return;

    const float* qp = query + ((size_t)b * M + m) * 3;
    const float qx = qp[0], qy = qp[1], qz = qp[2];
    const float sq = sq3_rn(qx, qy, qz);

    float dk[K];
    int   ik[K];
#pragma unroll
    for (int j = 0; j < K; ++j) { dk[j] = INFINITY; ik[j] = 0x7fffffff; }

    const float* rb = ref + (size_t)b * N * 3;
    for (int n = lane; n < N; n += 64) {
        const float* rp = rb + (size_t)n * 3;
        float rx = rp[0], ry = rp[1], rz = rp[2];
        float sr = sq3_rn(rx, ry, rz);
        float dot = __fadd_rn(__fadd_rn(__fmul_rn(qx, rx), __fmul_rn(qy, ry)),
                              __fmul_rn(qz, rz));
        float d = __fadd_rn(__fsub_rn(sq, __fmul_rn(2.0f, dot)), sr);
        if (d < dk[K - 1]) {
            dk[K - 1] = d;
            ik[K - 1] = n;
#pragma unroll
            for (int j = K - 1; j > 0; --j) {
                if (dk[j] < dk[j - 1]) {
                    float tv = dk[j]; dk[j] = dk[j - 1]; dk[j - 1] = tv;
                    int   ti = ik[j]; ik[j] = ik[j - 1]; ik[j - 1] = ti;
                }
            }
        }
    }

    unsigned hiA[K], loA[K];
#pragma unroll
    for (int j = 0; j < K; ++j) { hiA[j] = ford(dk[j]); loA[j] = (unsigned)ik[j]; }

    int winner = 0;
    for (int r = 0; r < K; ++r) {
        unsigned bhi, blo;
        wave_argmin_u32pair(hiA[0], loA[0], bhi, blo);
        if (lane == r) winner = (int)blo;
        if (hiA[0] == bhi && loA[0] == blo) {
#pragma unroll
            for (int j = 0; j < K - 1; ++j) { hiA[j] = hiA[j + 1]; loA[j] = loA[j + 1]; }
            hiA[K - 1] = 0xFFFFFFFFu;
            loA[K - 1] = 0xFFFFFFFFu;
        }
    }
    int* op = nidx + ((size_t)b * M + m) * K;
    if (lane < K) op[lane] = winner;
}

// ---------------------------------------------------------------------------
// FUSED KNN + SetConv, ALL dims compile-time (round-10 verified).
// ---------------------------------------------------------------------------
template <int K, int Cin, int C1, int C2>
__global__ __launch_bounds__(256)
void setconv_full(const float* __restrict__ ref_xyz, int N,
                  const float* __restrict__ ref_feat,
                  const float* __restrict__ new_xyz, int M,
                  const float* __restrict__ W0, const float* __restrict__ b0,
                  const float* __restrict__ W1, const float* __restrict__ b1,
                  float* __restrict__ out)
{
    constexpr int Cin3 = Cin + 3;
    const int b = blockIdx.y;
    const int tid = threadIdx.x;
    const int lane = tid & 63, ty = tid >> 6;
    const int m = blockIdx.x * 4 + ty;

    extern __shared__ float sm[];
    int*   nidx_s = (int*)sm;                 // [4][K]
    float* hb  = sm + 4 * K;                  // [4][K*Cin3]
    float* h1b = hb + 4 * K * Cin3;           // [4][K*C1]
    float* h  = hb  + ty * K * Cin3;
    float* h1 = h1b + ty * K * C1;

    const size_t qg = (size_t)b * M + m;
    const float* qp = new_xyz + qg * 3;
    const float qx = qp[0], qy = qp[1], qz = qp[2];

    {
        const float sq = sq3_rn(qx, qy, qz);
        float dk[K]; int ik[K];
#pragma unroll
        for (int j = 0; j < K; ++j) { dk[j] = INFINITY; ik[j] = 0x7fffffff; }
        const float* rb = ref_xyz + (size_t)b * N * 3;
        for (int n = lane; n < N; n += 64) {
            const float* rp = rb + (size_t)n * 3;
            float rx = rp[0], ry = rp[1], rz = rp[2];
            float sr = sq3_rn(rx, ry, rz);
            float dot = __fadd_rn(__fadd_rn(__fmul_rn(qx, rx), __fmul_rn(qy, ry)),
                                  __fmul_rn(qz, rz));
            float d = __fadd_rn(__fsub_rn(sq, __fmul_rn(2.0f, dot)), sr);
            if (d < dk[K - 1]) {
                dk[K - 1] = d;
                ik[K - 1] = n;
#pragma unroll
                for (int j = K - 1; j > 0; --j) {
                    if (dk[j] < dk[j - 1]) {
                        float tv = dk[j]; dk[j] = dk[j - 1]; dk[j - 1] = tv;
                        int   ti = ik[j]; ik[j] = ik[j - 1]; ik[j - 1] = ti;
                    }
                }
            }
        }
        unsigned hiA[K], loA[K];
#pragma unroll
        for (int j = 0; j < K; ++j) { hiA[j] = ford(dk[j]); loA[j] = (unsigned)ik[j]; }
        int winner = 0;
        for (int r = 0; r < K; ++r) {
            unsigned bhi, blo;
            wave_argmin_u32pair(hiA[0], loA[0], bhi, blo);
            if (lane == r) winner = (int)blo;
            if (hiA[0] == bhi && loA[0] == blo) {
#pragma unroll
                for (int j = 0; j < K - 1; ++j) { hiA[j] = hiA[j + 1]; loA[j] = loA[j + 1]; }
                hiA[K - 1] = 0xFFFFFFFFu;
                loA[K - 1] = 0xFFFFFFFFu;
            }
        }
        if (lane < K) nidx_s[ty * K + lane] = winner;
    }
    __syncthreads();

    for (int j = 0; j < K; ++j) {
        int n = nidx_s[ty * K + j];
        const float* xp = ref_xyz + ((size_t)b * N + n) * 3;
        const float* fp = ref_feat + ((size_t)b * N + n) * Cin;
        for (int i = lane; i < Cin3; i += 64) {
            float v;
            if (i == 0)      v = __fsub_rn(xp[0], qx);
            else if (i == 1) v = __fsub_rn(xp[1], qy);
            else if (i == 2) v = __fsub_rn(xp[2], qz);
            else             v = fp[i - 3];
            h[j * Cin3 + i] = v;
        }
    }
    __syncthreads();

#pragma unroll
    for (int c0 = 0; c0 < C1; c0 += 64) {
        int c = c0 + lane;
        bool act = c < C1;
        float acc[K];
        float bias = act ? b0[c] : 0.0f;
#pragma unroll
        for (int j = 0; j < K; ++j) acc[j] = bias;
        for (int i = 0; i < Cin3; ++i) {
            float w = act ? W0[i * C1 + c] : 0.0f;
#pragma unroll
            for (int j = 0; j < K; ++j) acc[j] = fmaf(h[j * Cin3 + i], w, acc[j]);
        }
        if (act) {
#pragma unroll
            for (int j = 0; j < K; ++j) h1[j * C1 + c] = fmaxf(acc[j], 0.0f);
        }
    }
    __syncthreads();

#pragma unroll
    for (int c0 = 0; c0 < C2; c0 += 64) {
        int c = c0 + lane;
        bool act = c < C2;
        float acc[K];
        float bias = act ? b1[c] : 0.0f;
#pragma unroll
        for (int j = 0; j < K; ++j) acc[j] = bias;
        for (int i = 0; i < C1; ++i) {
            float w = act ? W1[i * C2 + c] : 0.0f;
#pragma unroll
            for (int j = 0; j < K; ++j) acc[j] = fmaf(h1[j * C1 + i], w, acc[j]);
        }
        if (act) {
            float mv = acc[0];
#pragma unroll
            for (int j = 1; j < K; ++j) mv = fmaxf(mv, acc[j]);
            out[qg * C2 + c] = fmaxf(mv, 0.0f);
        }
    }
}

// ---------------------------------------------------------------------------
// SetUpConv APPLY (nidx precomputed by knn_wave), dims compile-time.
// 256-thread block = 4 waves = 4 fine queries, per-wave LDS slices.
// LDS: float h[4][K*Cc3]; float g[4][C1+Cf].
// ---------------------------------------------------------------------------
template <int K, int Cc, int Cf, int C1, int C2>
__global__ __launch_bounds__(256)
void upconv_apply(const float* __restrict__ cxyz, int Nc,
                  const float* __restrict__ cf,
                  const float* __restrict__ fxyz, int M,
                  const float* __restrict__ ff,
                  const int* __restrict__ nidx,
                  const float* __restrict__ W1, const float* __restrict__ b1,
                  const float* __restrict__ W2, const float* __restrict__ b2,
                  float* __restrict__ out)
{
    constexpr int Cc3 = Cc + 3;
    const int b = blockIdx.y;
    const int tid = threadIdx.x;
    const int lane = tid & 63, ty = tid >> 6;
    const int m = blockIdx.x * 4 + ty;

    extern __shared__ float sm[];
    float* hb = sm;                           // [4][K*Cc3]
    float* gb = hb + 4 * K * Cc3;             // [4][C1+Cf]
    float* h = hb + ty * K * Cc3;
    float* g = gb + ty * (C1 + Cf);

    const size_t qg = (size_t)b * M + m;
    const float* qp = fxyz + qg * 3;
    const float qx = qp[0], qy = qp[1], qz = qp[2];

    for (int j = 0; j < K; ++j) {
        int n = nidx[qg * K + j];
        const float* xp = cxyz + ((size_t)b * Nc + n) * 3;
        const float* fp = cf + ((size_t)b * Nc + n) * Cc;
        for (int i = lane; i < Cc3; i += 64) {
            float v;
            if (i == 0)      v = __fsub_rn(xp[0], qx);
            else if (i == 1) v = __fsub_rn(xp[1], qy);
            else if (i == 2) v = __fsub_rn(xp[2], qz);
            else             v = fp[i - 3];
            h[j * Cc3 + i] = v;
        }
    }
    for (int i = lane; i < Cf; i += 64) g[C1 + i] = ff[qg * Cf + i];
    __syncthreads();

#pragma unroll
    for (int c0 = 0; c0 < C1; c0 += 64) {
        int c = c0 + lane;
        bool act = c < C1;
        float acc[K];
        float bias = act ? b1[c] : 0.0f;
#pragma unroll
        for (int j = 0; j < K; ++j) acc[j] = bias;
        for (int i = 0; i < Cc3; ++i) {
            float w = act ? W1[i * C1 + c] : 0.0f;
#pragma unroll
            for (int j = 0; j < K; ++j) acc[j] = fmaf(h[j * Cc3 + i], w, acc[j]);
        }
        if (act) {
            float mv = acc[0];
#pragma unroll
            for (int j = 1; j < K; ++j) mv = fmaxf(mv, acc[j]);
            g[c] = fmaxf(mv, 0.0f);
        }
    }
    __syncthreads();

    constexpr int Cg = C1 + Cf;
#pragma unroll
    for (int c0 = 0; c0 < C2; c0 += 64) {
        int c = c0 + lane;
        bool act = c < C2;
        float acc = act ? b2[c] : 0.0f;
        for (int i = 0; i < Cg; ++i) {
            float w = act ? W2[i * C2 + c] : 0.0f;
            acc = fmaf(g[i], w, acc);
        }
        if (act) out[qg * C2 + c] = fmaxf(acc, 0.0f);
    }
}

// ---------------------------------------------------------------------------
// f0 = relu(feat @ d0_W + d0_b), 3 -> 32 channels.
// ---------------------------------------------------------------------------
__global__ void f0_kernel(const float* __restrict__ feat, const float* __restrict__ W,
                          const float* __restrict__ bias, float* __restrict__ out)
{
    int t = blockIdx.x * blockDim.x + threadIdx.x;
    int n = t >> 5, c = t & 31;
    const float* f = feat + (size_t)n * 3;
    float acc = bias[c];
    acc = fmaf(f[0], W[c], acc);
    acc = fmaf(f[1], W[32 + c], acc);
    acc = fmaf(f[2], W[64 + c], acc);
    out[t] = fmaxf(acc, 0.0f);
}

// ---------------------------------------------------------------------------

extern "C" void kernel_launch(void* const* d_in, const int* in_sizes, int n_in,
                              void* d_out, int out_size, void* d_ws, size_t ws_size,
                              hipStream_t stream)
{
    const float* pc    = (const float*)d_in[0];
    const float* feat  = (const float*)d_in[1];
    const float* d0_W  = (const float*)d_in[2];
    const float* d0_b  = (const float*)d_in[3];
    const float* d1_W0 = (const float*)d_in[4];
    const float* d1_b0 = (const float*)d_in[5];
    const float* d1_W1 = (const float*)d_in[6];
    const float* d1_b1 = (const float*)d_in[7];
    const float* d2_W0 = (const float*)d_in[8];
    const float* d2_b0 = (const float*)d_in[9];
    const float* d2_W1 = (const float*)d_in[10];
    const float* d2_b1 = (const float*)d_in[11];
    const float* d3_W0 = (const float*)d_in[12];
    const float* d3_b0 = (const float*)d_in[13];
    const float* d3_W1 = (const float*)d_in[14];
    const float* d3_b1 = (const float*)d_in[15];
    const float* d4_W0 = (const float*)d_in[16];
    const float* d4_b0 = (const float*)d_in[17];
    const float* d4_W1 = (const float*)d_in[18];
    const float* d4_b1 = (const float*)d_in[19];
    const float* u4_W1 = (const float*)d_in[20];
    const float* u4_b1 = (const float*)d_in[21];
    const float* u4_W2 = (const float*)d_in[22];
    const float* u4_b2 = (const float*)d_in[23];
    const float* u3_W1 = (const float*)d_in[24];
    const float* u3_b1 = (const float*)d_in[25];
    const float* u3_W2 = (const float*)d_in[26];
    const float* u3_b2 = (const float*)d_in[27];
    const float* u2_W1 = (const float*)d_in[28];
    const float* u2_b1 = (const float*)d_in[29];
    const float* u2_W2 = (const float*)d_in[30];
    const float* u2_b2 = (const float*)d_in[31];
    const float* u1_W1 = (const float*)d_in[32];
    const float* u1_b1 = (const float*)d_in[33];
    const float* u1_W2 = (const float*)d_in[34];
    const float* u1_b2 = (const float*)d_in[35];

    float* out = (float*)d_out;
    float* o_x1 = out + 0;       // 12288
    float* o_x2 = out + 12288;   // 3072
    float* o_x3 = out + 15360;   // 768
    float* o_i1 = out + 16128;   // 4096
    float* o_i2 = out + 20224;   // 1024
    float* o_i3 = out + 21248;   // 256
    float* o_u0 = out + 21504;   // 524288
    float* o_u1 = out + 545792;  // 262144
    float* o_u2 = out + 807936;  // 131072
    float* o_u3 = out + 939008;  // 49152

    float* w = (float*)d_ws;
    float* f0 = w; w += 2 * 8192 * 32;
    float* f1 = w; w += 2 * 2048 * 64;
    float* f2 = w; w += 2 * 512 * 128;
    float* f3 = w; w += 2 * 128 * 192;
    float* f4 = w; w += 2 * 64 * 192;
    float* x4 = w; w += 2 * 64 * 3;
    int* nidx_u0 = (int*)w; w += 2 * 8192 * 8;
    int* nidx_u1 = (int*)w; w += 2 * 2048 * 8;
    int* nidx_u2 = (int*)w; w += 2 * 512 * 8;
    int* nidx_u3 = (int*)w; w += 2 * 128 * 8;

    const int B = 2;
    const dim3 kb(64, KNN_QPB);

    // one-time setup: LDS caps + streams + events (DisableTiming; capture-safe)
    static bool init_done = false;
    static hipStream_t s2 = nullptr, s3 = nullptr;
    static hipEvent_t evFork = nullptr, evX1 = nullptr, evX2 = nullptr,
                      evX3 = nullptr, evX4 = nullptr, evK = nullptr,
                      evJoin = nullptr;
    if (!init_done) {
        (void)hipFuncSetAttribute((const void*)fps_block<256, 32>,
                                  hipFuncAttributeMaxDynamicSharedMemorySize,
                                  8192 * 3 * 4 + 2048 * 4 * 4);          // 131072
        (void)hipFuncSetAttribute((const void*)setconv_full<16, 128, 128, 192>,
                                  hipFuncAttributeMaxDynamicSharedMemorySize,
                                  (4 * 16 + 4 * 16 * 131 + 4 * 16 * 128) * 4); // 66560
        (void)hipFuncSetAttribute((const void*)setconv_full<16, 192, 192, 192>,
                                  hipFuncAttributeMaxDynamicSharedMemorySize,
                                  (4 * 16 + 4 * 16 * 195 + 4 * 16 * 192) * 4); // 99328
        (void)hipStreamCreateWithFlags(&s2, hipStreamNonBlocking);
        (void)hipStreamCreateWithFlags(&s3, hipStreamNonBlocking);
        (void)hipEventCreateWithFlags(&evFork, hipEventDisableTiming);
        (void)hipEventCreateWithFlags(&evX1, hipEventDisableTiming);
        (void)hipEventCreateWithFlags(&evX2, hipEventDisableTiming);
        (void)hipEventCreateWithFlags(&evX3, hipEventDisableTiming);
        (void)hipEventCreateWithFlags(&evX4, hipEventDisableTiming);
        (void)hipEventCreateWithFlags(&evK, hipEventDisableTiming);
        (void)hipEventCreateWithFlags(&evJoin, hipEventDisableTiming);
        init_done = true;
    }

    // ---- fork ----
    (void)hipEventRecord(evFork, stream);
    (void)hipStreamWaitEvent(s2, evFork, 0);
    (void)hipStreamWaitEvent(s3, evFork, 0);

    // f0 on s2, concurrent with fps1
    f0_kernel<<<(2 * 8192 * 32) / 256, 256, 0, s2>>>(feat, d0_W, d0_b, f0);

    // ---- fps chain on main stream ----
    fps_block<256, 32><<<B, 256, 8192 * 3 * 4 + 2048 * 4 * 4, stream>>>(pc, 2048, o_x1, o_i1);
    (void)hipEventRecord(evX1, stream);
    fps_block<256, 8><<<B, 256, 2048 * 3 * 4 + 512 * 4 * 4, stream>>>(o_x1, 512, o_x2, o_i2);
    (void)hipEventRecord(evX2, stream);
    fps_wave<8><<<B, 64, 512 * 3 * 4 + 128 * 4 * 4, stream>>>(o_x2, 128, o_x3, o_i3);
    (void)hipEventRecord(evX3, stream);
    fps_wave<2><<<B, 64, 128 * 3 * 4 + 64 * 4 * 4, stream>>>(o_x3, 64, x4, nullptr);
    (void)hipEventRecord(evX4, stream);

    // ---- hoisted up-path KNNs on s3 (overlap with down-path convs) ----
    (void)hipStreamWaitEvent(s3, evX1, 0);   // pc + o_x1
    knn_wave<8><<<dim3(8192 / KNN_QPB, B), kb, 0, s3>>>(pc, 8192, o_x1, 2048, nidx_u0);
    (void)hipStreamWaitEvent(s3, evX2, 0);   // o_x1 + o_x2
    knn_wave<8><<<dim3(2048 / KNN_QPB, B), kb, 0, s3>>>(o_x1, 2048, o_x2, 512, nidx_u1);
    (void)hipStreamWaitEvent(s3, evX3, 0);   // o_x2 + o_x3
    knn_wave<8><<<dim3(512 / KNN_QPB, B), kb, 0, s3>>>(o_x2, 512, o_x3, 128, nidx_u2);
    (void)hipStreamWaitEvent(s3, evX4, 0);   // o_x3 + x4
    knn_wave<8><<<dim3(128 / KNN_QPB, B), kb, 0, s3>>>(o_x3, 128, x4, 64, nidx_u3);
    (void)hipEventRecord(evK, s3);

    // ---- down path on s2 (fused knn+setconv, compile-time dims) ----
    (void)hipStreamWaitEvent(s2, evX1, 0);   // o_x1 ready
    setconv_full<16, 32, 32, 64><<<dim3(2048 / 4, B), 256,
        (4 * 16 + 4 * 16 * 35 + 4 * 16 * 32) * 4, s2>>>(
        pc, 8192, f0, o_x1, 2048, d1_W0, d1_b0, d1_W1, d1_b1, f1);
    (void)hipStreamWaitEvent(s2, evX2, 0);   // o_x2 ready
    setconv_full<16, 64, 64, 128><<<dim3(512 / 4, B), 256,
        (4 * 16 + 4 * 16 * 67 + 4 * 16 * 64) * 4, s2>>>(
        o_x1, 2048, f1, o_x2, 512, d2_W0, d2_b0, d2_W1, d2_b1, f2);
    (void)hipStreamWaitEvent(s2, evX3, 0);   // o_x3 ready
    setconv_full<16, 128, 128, 192><<<dim3(128 / 4, B), 256,
        (4 * 16 + 4 * 16 * 131 + 4 * 16 * 128) * 4, s2>>>(
        o_x2, 512, f2, o_x3, 128, d3_W0, d3_b0, d3_W1, d3_b1, f3);
    (void)hipStreamWaitEvent(s2, evX4, 0);   // x4 ready
    setconv_full<16, 192, 192, 192><<<dim3(64 / 4, B), 256,
        (4 * 16 + 4 * 16 * 195 + 4 * 16 * 192) * 4, s2>>>(
        o_x3, 128, f3, x4, 64, d4_W0, d4_b0, d4_W1, d4_b1, f4);

    // ---- up path applies on s2 (consume precomputed nidx) ----
    (void)hipStreamWaitEvent(s2, evK, 0);    // all nidx ready
    upconv_apply<8, 192, 192, 192, 192><<<dim3(128 / 4, B), 256,
        (4 * 8 * 195 + 4 * (192 + 192)) * 4, s2>>>(
        x4, 64, f4, o_x3, 128, f3, nidx_u3, u4_W1, u4_b1, u4_W2, u4_b2, o_u3);
    upconv_apply<8, 192, 128, 128, 128><<<dim3(512 / 4, B), 256,
        (4 * 8 * 195 + 4 * (128 + 128)) * 4, s2>>>(
        o_x3, 128, o_u3, o_x2, 512, f2, nidx_u2, u3_W1, u3_b1, u3_W2, u3_b2, o_u2);
    upconv_apply<8, 128, 64, 64, 64><<<dim3(2048 / 4, B), 256,
        (4 * 8 * 131 + 4 * (64 + 64)) * 4, s2>>>(
        o_x2, 512, o_u2, o_x1, 2048, f1, nidx_u1, u2_W1, u2_b1, u2_W2, u2_b2, o_u1);
    upconv_apply<8, 64, 32, 32, 32><<<dim3(8192 / 4, B), 256,
        (4 * 8 * 67 + 4 * (32 + 32)) * 4, s2>>>(
        o_x1, 2048, o_u1, pc, 8192, f0, nidx_u0, u1_W1, u1_b1, u1_W2, u1_b2, o_u0);

    // ---- join ----
    (void)hipEventRecord(evJoin, s2);
    (void)hipStreamWaitEvent(stream, evJoin, 0);
}

// Round 14
// 2780.509 us; speedup vs baseline: 4.0445x; 1.0161x over previous
//
#include <hip/hip_runtime.h>
#include <cstdint>
#include <cstddef>

// ---------------------------------------------------------------------------
// FlowNet3D-style encoder/decoder pyramid (GenFlow_unit_mask).
// FINAL (round-11 config, best verified 2789us):
//  - fps level-1: round-5 single-CU kernel (1778us) — structural floor
//    (7 alternatives probed: pk-f32, T=512, LDS-stream, hybrid-residency,
//     f64-reduce, 4-CU distributed(6x worse) all regressed).
//  - fused dim-templated knn+conv kernels (de-spilled: VGPR 24->56, -440us).
//  - two-stream fork-join: f0 || fps1; fps2/3/4 || sc1-sc3 (-130us).
// ---------------------------------------------------------------------------

static __device__ __forceinline__ float sq3_rn(float x, float y, float z) {
    // ((x*x + y*y) + z*z) strict IEEE (no fma) to bit-match numpy
    return __fadd_rn(__fadd_rn(__fmul_rn(x, x), __fmul_rn(y, y)), __fmul_rn(z, z));
}

// monotone float -> uint map (handles negatives from catastrophic cancellation)
static __device__ __forceinline__ unsigned int ford(float f) {
    unsigned int u = __float_as_uint(f);
    return u ^ ((u >> 31) ? 0xFFFFFFFFu : 0x80000000u);
}

// ---------------------------------------------------------------------------
// Branchless DPP wave-64 u32 reductions. Result lands in lane 63.
// bound_ctrl=false -> invalid-source lanes keep old value (identity).
// ---------------------------------------------------------------------------
template <int CTRL>
static __device__ __forceinline__ void dpp_umax_step(unsigned& v) {
    unsigned t = (unsigned)__builtin_amdgcn_update_dpp((int)v, (int)v, CTRL, 0xf, 0xf, false);
    v = (t > v) ? t : v;   // v_max_u32
}
template <int CTRL>
static __device__ __forceinline__ void dpp_umin_step(unsigned& v) {
    unsigned t = (unsigned)__builtin_amdgcn_update_dpp((int)v, (int)v, CTRL, 0xf, 0xf, false);
    v = (t < v) ? t : v;   // v_min_u32
}
static __device__ __forceinline__ unsigned dpp_wave_umax(unsigned v) {
    dpp_umax_step<0x111>(v);  // row_shr:1
    dpp_umax_step<0x112>(v);  // row_shr:2
    dpp_umax_step<0x114>(v);  // row_shr:4
    dpp_umax_step<0x118>(v);  // row_shr:8
    dpp_umax_step<0x142>(v);  // row_bcast:15
    dpp_umax_step<0x143>(v);  // row_bcast:31
    return v;                 // full max in lane 63
}
static __device__ __forceinline__ unsigned dpp_wave_umin(unsigned v) {
    dpp_umin_step<0x111>(v);
    dpp_umin_step<0x112>(v);
    dpp_umin_step<0x114>(v);
    dpp_umin_step<0x118>(v);
    dpp_umin_step<0x142>(v);
    dpp_umin_step<0x143>(v);
    return v;
}
static __device__ __forceinline__ void wave_argmin_u32pair(unsigned hi, unsigned lo,
                                                          unsigned& whi, unsigned& wlo) {
    unsigned h = dpp_wave_umin(hi);
    whi = (unsigned)__builtin_amdgcn_readlane((int)h, 63);
    unsigned cand = (hi == whi) ? lo : 0xFFFFFFFFu; // real lo (index) < 2^31
    unsigned l = dpp_wave_umin(cand);
    wlo = (unsigned)__builtin_amdgcn_readlane((int)l, 63);
}

// ---------------------------------------------------------------------------
// FPS, multi-wave single-CU version (round-5 floor: ~1778us at L1).
// THREAD-MAJOR mapping: thread t owns points [t*P, (t+1)*P). Within a wave,
// smaller lane => strictly smaller point indices, so among value-ties the
// FIRST matching lane (ballot+ctz) is the exact numpy first-occurrence.
// Per-thread scan: 4 independent accumulators over contiguous quarters.
// Wave reduce = ONE 6-step DPP u32-max + readlane + ballot + readlane(bj,L).
// Cross-wave merge: max hi, min bp among matches (wave ranges disjoint).
// Zero global ops in the serial loop; ONE barrier/iter (parity slots).
// Dynamic LDS = N*3*4 (mirror) + M*4*4 (out).
// ---------------------------------------------------------------------------
template <int T, int P>
__global__ __launch_bounds__(T) __attribute__((amdgpu_waves_per_eu(1, 1)))
void fps_block(const float* __restrict__ xyz, int M,
               float* __restrict__ new_xyz, float* __restrict__ out_idx)
{
    static_assert(P % 4 == 0, "P must be a multiple of 4");
    constexpr int N = T * P;
    constexpr int NW = T / 64;
    constexpr int Q = P / 4;
    const int b = blockIdx.x;
    const int t = threadIdx.x;
    const int lane = t & 63, wave = t >> 6;

    __shared__ uint2 s_slot[2][NW];   // {hi, bp} per wave, parity-buffered
    extern __shared__ float sm[];
    float* spts = sm;           // N*3 point mirror
    float* sout = sm + N * 3;   // M*4: cx,cy,cz,(float)idx

    const float* x0 = xyz + (size_t)b * N * 3;
    for (int i = t; i < N * 3; i += T) spts[i] = x0[i];

    float px[P], py[P], pz[P], dist[P];
#pragma unroll
    for (int j = 0; j < P; ++j) {
        int p = t * P + j;          // thread-major
        px[j] = x0[p * 3 + 0];
        py[j] = x0[p * 3 + 1];
        pz[j] = x0[p * 3 + 2];
        dist[j] = 1e10f;
    }
    __syncthreads();

    int far = 0;
    for (int m = 0; m < M; ++m) {
        float cx = spts[far * 3 + 0];
        float cy = spts[far * 3 + 1];
        float cz = spts[far * 3 + 2];
        if (t == 0) {
            float* so = sout + m * 4;
            so[0] = cx; so[1] = cy; so[2] = cz; so[3] = (float)far;
        }
        float bv[4]; int bj[4];
#pragma unroll
        for (int a = 0; a < 4; ++a) { bv[a] = -1.0f; bj[a] = 0; }
#pragma unroll
        for (int j = 0; j < Q; ++j) {
#pragma unroll
            for (int a = 0; a < 4; ++a) {
                int idx = a * Q + j;
                float dx = __fsub_rn(px[idx], cx);
                float dy = __fsub_rn(py[idx], cy);
                float dz = __fsub_rn(pz[idx], cz);
                float d  = sq3_rn(dx, dy, dz);
                float nd = fminf(dist[idx], d);
                dist[idx] = nd;
                bj[a] = (nd > bv[a]) ? idx : bj[a];   // strict >: first occurrence
                bv[a] = fmaxf(bv[a], nd);
            }
        }
        float bvv = bv[0]; int bjj = bj[0];
#pragma unroll
        for (int a = 1; a < 4; ++a) {
            bjj = (bv[a] > bvv) ? bj[a] : bjj;        // tie keeps lower quarter
            bvv = fmaxf(bvv, bv[a]);
        }
        unsigned hi = __float_as_uint(bvv);           // bvv >= 0 -> monotone bits
        unsigned h = dpp_wave_umax(hi);
        unsigned whi = (unsigned)__builtin_amdgcn_readlane((int)h, 63);
        unsigned long long mk = __ballot(hi == whi);  // nonempty (max matches self)
        int L = (int)__builtin_ctzll(mk);             // min lane = min point idx
        int bjL = __builtin_amdgcn_readlane(bjj, L);
        unsigned wbp = (unsigned)((((wave << 6) + L) * P) + bjL);
        if (lane == 0) s_slot[m & 1][wave] = make_uint2(whi, wbp);
        __syncthreads();
        uint2 sv[NW];
#pragma unroll
        for (int w2 = 0; w2 < NW; ++w2) sv[w2] = s_slot[m & 1][w2];
        unsigned bhi = 0u;
#pragma unroll
        for (int w2 = 0; w2 < NW; ++w2) bhi = (sv[w2].x > bhi) ? sv[w2].x : bhi;
        unsigned blo = 0xFFFFFFFFu;
#pragma unroll
        for (int w2 = 0; w2 < NW; ++w2) {
            unsigned c = (sv[w2].x == bhi) ? sv[w2].y : 0xFFFFFFFFu;
            blo = (c < blo) ? c : blo;                // wave ranges disjoint+ordered
        }
        far = (int)blo;
    }

    // coalesced flush of accumulated outputs
    __syncthreads();
    for (int i = t; i < M * 3; i += T) {
        int mm = i / 3, c = i - mm * 3;
        new_xyz[(size_t)b * M * 3 + i] = sout[mm * 4 + c];
    }
    if (out_idx) {
        for (int i = t; i < M; i += T)
            out_idx[(size_t)b * M + i] = sout[i * 4 + 3];
    }
}

// ---------------------------------------------------------------------------
// FPS, single-wave version (round-5): thread-major mapping, split
// accumulators, single-phase DPP + ballot (min lane = min idx, exact).
// Dynamic LDS = N*3*4 + M*4*4.
// ---------------------------------------------------------------------------
template <int P>
__global__ __launch_bounds__(64) __attribute__((amdgpu_waves_per_eu(1, 1)))
void fps_wave(const float* __restrict__ xyz, int M,
              float* __restrict__ new_xyz, float* __restrict__ out_idx)
{
    constexpr int NA = (P % 4 == 0) ? 4 : 2;
    constexpr int Q = P / NA;
    const int b = blockIdx.x;
    const int lane = threadIdx.x;
    const int N = 64 * P;
    extern __shared__ float sm[];
    float* spts = sm;           // N*3
    float* sout = sm + N * 3;   // M*4
    const float* x0 = xyz + (size_t)b * N * 3;

    for (int i = lane; i < N * 3; i += 64) spts[i] = x0[i];

    float px[P], py[P], pz[P], dist[P];
#pragma unroll
    for (int j = 0; j < P; ++j) {
        int p = lane * P + j;       // thread-major
        px[j] = x0[p * 3 + 0];
        py[j] = x0[p * 3 + 1];
        pz[j] = x0[p * 3 + 2];
        dist[j] = 1e10f;
    }
    __syncthreads();

    int far = 0;
    for (int m = 0; m < M; ++m) {
        float cx = spts[far * 3 + 0];
        float cy = spts[far * 3 + 1];
        float cz = spts[far * 3 + 2];
        if (lane == 0) {
            float* so = sout + m * 4;
            so[0] = cx; so[1] = cy; so[2] = cz; so[3] = (float)far;
        }
        float bv[NA]; int bj[NA];
#pragma unroll
        for (int a = 0; a < NA; ++a) { bv[a] = -1.0f; bj[a] = 0; }
#pragma unroll
        for (int j = 0; j < Q; ++j) {
#pragma unroll
            for (int a = 0; a < NA; ++a) {
                int idx = a * Q + j;
                float dx = __fsub_rn(px[idx], cx);
                float dy = __fsub_rn(py[idx], cy);
                float dz = __fsub_rn(pz[idx], cz);
                float d  = sq3_rn(dx, dy, dz);
                float nd = fminf(dist[idx], d);
                dist[idx] = nd;
                bj[a] = (nd > bv[a]) ? idx : bj[a];
                bv[a] = fmaxf(bv[a], nd);
            }
        }
        float bvv = bv[0]; int bjj = bj[0];
#pragma unroll
        for (int a = 1; a < NA; ++a) {
            bjj = (bv[a] > bvv) ? bj[a] : bjj;
            bvv = fmaxf(bvv, bv[a]);
        }
        unsigned hi = __float_as_uint(bvv);
        unsigned h = dpp_wave_umax(hi);
        unsigned whi = (unsigned)__builtin_amdgcn_readlane((int)h, 63);
        unsigned long long mk = __ballot(hi == whi);
        int L = (int)__builtin_ctzll(mk);
        int bjL = __builtin_amdgcn_readlane(bjj, L);
        far = L * P + bjL;
    }

    __syncthreads();
    for (int i = lane; i < M * 3; i += 64) {
        int mm = i / 3, c = i - mm * 3;
        new_xyz[(size_t)b * M * 3 + i] = sout[mm * 4 + c];
    }
    if (out_idx) {
        for (int i = lane; i < M; i += 64)
            out_idx[(size_t)b * M + i] = sout[i * 4 + 3];
    }
}

// ---------------------------------------------------------------------------
// FUSED KNN + SetConv, ALL dims compile-time. 256-thread block = 4 waves =
// 4 queries. Wave ty computes the exact top-K for its query into LDS, then
// runs the setconv MLP for the same query. Same math/order as split kernels.
// LDS: int nidx[4][K]; float h[4][K*Cin3]; float h1[4][K*C1].
// ---------------------------------------------------------------------------
template <int K, int Cin, int C1, int C2>
__global__ __launch_bounds__(256)
void setconv_full(const float* __restrict__ ref_xyz, int N,
                  const float* __restrict__ ref_feat,
                  const float* __restrict__ new_xyz, int M,
                  const float* __restrict__ W0, const float* __restrict__ b0,
                  const float* __restrict__ W1, const float* __restrict__ b1,
                  float* __restrict__ out)
{
    constexpr int Cin3 = Cin + 3;
    const int b = blockIdx.y;
    const int tid = threadIdx.x;
    const int lane = tid & 63, ty = tid >> 6;
    const int m = blockIdx.x * 4 + ty;

    extern __shared__ float sm[];
    int*   nidx_s = (int*)sm;                 // [4][K]
    float* hb  = sm + 4 * K;                  // [4][K*Cin3]
    float* h1b = hb + 4 * K * Cin3;           // [4][K*C1]
    float* h  = hb  + ty * K * Cin3;
    float* h1 = h1b + ty * K * C1;

    const size_t qg = (size_t)b * M + m;
    const float* qp = new_xyz + qg * 3;
    const float qx = qp[0], qy = qp[1], qz = qp[2];

    // ---- KNN phase (exact knn_wave body) ----
    {
        const float sq = sq3_rn(qx, qy, qz);
        float dk[K]; int ik[K];
#pragma unroll
        for (int j = 0; j < K; ++j) { dk[j] = INFINITY; ik[j] = 0x7fffffff; }
        const float* rb = ref_xyz + (size_t)b * N * 3;
        for (int n = lane; n < N; n += 64) {
            const float* rp = rb + (size_t)n * 3;
            float rx = rp[0], ry = rp[1], rz = rp[2];
            float sr = sq3_rn(rx, ry, rz);
            float dot = __fadd_rn(__fadd_rn(__fmul_rn(qx, rx), __fmul_rn(qy, ry)),
                                  __fmul_rn(qz, rz));
            float d = __fadd_rn(__fsub_rn(sq, __fmul_rn(2.0f, dot)), sr);
            if (d < dk[K - 1]) {
                dk[K - 1] = d;
                ik[K - 1] = n;
#pragma unroll
                for (int j = K - 1; j > 0; --j) {
                    if (dk[j] < dk[j - 1]) {
                        float tv = dk[j]; dk[j] = dk[j - 1]; dk[j - 1] = tv;
                        int   ti = ik[j]; ik[j] = ik[j - 1]; ik[j - 1] = ti;
                    }
                }
            }
        }
        unsigned hiA[K], loA[K];
#pragma unroll
        for (int j = 0; j < K; ++j) { hiA[j] = ford(dk[j]); loA[j] = (unsigned)ik[j]; }
        int winner = 0;
        for (int r = 0; r < K; ++r) {
            unsigned bhi, blo;
            wave_argmin_u32pair(hiA[0], loA[0], bhi, blo);
            if (lane == r) winner = (int)blo;
            if (hiA[0] == bhi && loA[0] == blo) {
#pragma unroll
                for (int j = 0; j < K - 1; ++j) { hiA[j] = hiA[j + 1]; loA[j] = loA[j + 1]; }
                hiA[K - 1] = 0xFFFFFFFFu;
                loA[K - 1] = 0xFFFFFFFFu;
            }
        }
        if (lane < K) nidx_s[ty * K + lane] = winner;
    }
    __syncthreads();

    // ---- gather phase ----
    for (int j = 0; j < K; ++j) {
        int n = nidx_s[ty * K + j];
        const float* xp = ref_xyz + ((size_t)b * N + n) * 3;
        const float* fp = ref_feat + ((size_t)b * N + n) * Cin;
        for (int i = lane; i < Cin3; i += 64) {
            float v;
            if (i == 0)      v = __fsub_rn(xp[0], qx);
            else if (i == 1) v = __fsub_rn(xp[1], qy);
            else if (i == 2) v = __fsub_rn(xp[2], qz);
            else             v = fp[i - 3];
            h[j * Cin3 + i] = v;
        }
    }
    __syncthreads();

    // ---- MLP layer 1 (compile-time bounds -> acc register-resident) ----
#pragma unroll
    for (int c0 = 0; c0 < C1; c0 += 64) {
        int c = c0 + lane;
        bool act = c < C1;
        float acc[K];
        float bias = act ? b0[c] : 0.0f;
#pragma unroll
        for (int j = 0; j < K; ++j) acc[j] = bias;
        for (int i = 0; i < Cin3; ++i) {
            float w = act ? W0[i * C1 + c] : 0.0f;
#pragma unroll
            for (int j = 0; j < K; ++j) acc[j] = fmaf(h[j * Cin3 + i], w, acc[j]);
        }
        if (act) {
#pragma unroll
            for (int j = 0; j < K; ++j) h1[j * C1 + c] = fmaxf(acc[j], 0.0f);
        }
    }
    __syncthreads();

    // ---- MLP layer 2 + max-pool ----
#pragma unroll
    for (int c0 = 0; c0 < C2; c0 += 64) {
        int c = c0 + lane;
        bool act = c < C2;
        float acc[K];
        float bias = act ? b1[c] : 0.0f;
#pragma unroll
        for (int j = 0; j < K; ++j) acc[j] = bias;
        for (int i = 0; i < C1; ++i) {
            float w = act ? W1[i * C2 + c] : 0.0f;
#pragma unroll
            for (int j = 0; j < K; ++j) acc[j] = fmaf(h1[j * C1 + i], w, acc[j]);
        }
        if (act) {
            float mv = acc[0];
#pragma unroll
            for (int j = 1; j < K; ++j) mv = fmaxf(mv, acc[j]);
            out[qg * C2 + c] = fmaxf(mv, 0.0f);
        }
    }
}

// ---------------------------------------------------------------------------
// FUSED KNN + SetUpConv, ALL dims compile-time. 4 waves = 4 fine queries.
// LDS: int nidx[4][K]; float h[4][K*Cc3]; float g[4][C1+Cf].
// ---------------------------------------------------------------------------
template <int K, int Cc, int Cf, int C1, int C2>
__global__ __launch_bounds__(256)
void upconv_full(const float* __restrict__ cxyz, int Nc,
                 const float* __restrict__ cf,
                 const float* __restrict__ fxyz, int M,
                 const float* __restrict__ ff,
                 const float* __restrict__ W1, const float* __restrict__ b1,
                 const float* __restrict__ W2, const float* __restrict__ b2,
                 float* __restrict__ out)
{
    constexpr int Cc3 = Cc + 3;
    const int b = blockIdx.y;
    const int tid = threadIdx.x;
    const int lane = tid & 63, ty = tid >> 6;
    const int m = blockIdx.x * 4 + ty;

    extern __shared__ float sm[];
    int*   nidx_s = (int*)sm;                 // [4][K]
    float* hb = sm + 4 * K;                   // [4][K*Cc3]
    float* gb = hb + 4 * K * Cc3;             // [4][C1+Cf]
    float* h = hb + ty * K * Cc3;
    float* g = gb + ty * (C1 + Cf);

    const size_t qg = (size_t)b * M + m;
    const float* qp = fxyz + qg * 3;
    const float qx = qp[0], qy = qp[1], qz = qp[2];

    // ---- KNN phase ----
    {
        const float sq = sq3_rn(qx, qy, qz);
        float dk[K]; int ik[K];
#pragma unroll
        for (int j = 0; j < K; ++j) { dk[j] = INFINITY; ik[j] = 0x7fffffff; }
        const float* rb = cxyz + (size_t)b * Nc * 3;
        for (int n = lane; n < Nc; n += 64) {
            const float* rp = rb + (size_t)n * 3;
            float rx = rp[0], ry = rp[1], rz = rp[2];
            float sr = sq3_rn(rx, ry, rz);
            float dot = __fadd_rn(__fadd_rn(__fmul_rn(qx, rx), __fmul_rn(qy, ry)),
                                  __fmul_rn(qz, rz));
            float d = __fadd_rn(__fsub_rn(sq, __fmul_rn(2.0f, dot)), sr);
            if (d < dk[K - 1]) {
                dk[K - 1] = d;
                ik[K - 1] = n;
#pragma unroll
                for (int j = K - 1; j > 0; --j) {
                    if (dk[j] < dk[j - 1]) {
                        float tv = dk[j]; dk[j] = dk[j - 1]; dk[j - 1] = tv;
                        int   ti = ik[j]; ik[j] = ik[j - 1]; ik[j - 1] = ti;
                    }
                }
            }
        }
        unsigned hiA[K], loA[K];
#pragma unroll
        for (int j = 0; j < K; ++j) { hiA[j] = ford(dk[j]); loA[j] = (unsigned)ik[j]; }
        int winner = 0;
        for (int r = 0; r < K; ++r) {
            unsigned bhi, blo;
            wave_argmin_u32pair(hiA[0], loA[0], bhi, blo);
            if (lane == r) winner = (int)blo;
            if (hiA[0] == bhi && loA[0] == blo) {
#pragma unroll
                for (int j = 0; j < K - 1; ++j) { hiA[j] = hiA[j + 1]; loA[j] = loA[j + 1]; }
                hiA[K - 1] = 0xFFFFFFFFu;
                loA[K - 1] = 0xFFFFFFFFu;
            }
        }
        if (lane < K) nidx_s[ty * K + lane] = winner;
    }
    __syncthreads();

    // ---- gather phase ----
    for (int j = 0; j < K; ++j) {
        int n = nidx_s[ty * K + j];
        const float* xp = cxyz + ((size_t)b * Nc + n) * 3;
        const float* fp = cf + ((size_t)b * Nc + n) * Cc;
        for (int i = lane; i < Cc3; i += 64) {
            float v;
            if (i == 0)      v = __fsub_rn(xp[0], qx);
            else if (i == 1) v = __fsub_rn(xp[1], qy);
            else if (i == 2) v = __fsub_rn(xp[2], qz);
            else             v = fp[i - 3];
            h[j * Cc3 + i] = v;
        }
    }
    for (int i = lane; i < Cf; i += 64) g[C1 + i] = ff[qg * Cf + i];
    __syncthreads();

    // ---- MLP1 + max-pool ----
#pragma unroll
    for (int c0 = 0; c0 < C1; c0 += 64) {
        int c = c0 + lane;
        bool act = c < C1;
        float acc[K];
        float bias = act ? b1[c] : 0.0f;
#pragma unroll
        for (int j = 0; j < K; ++j) acc[j] = bias;
        for (int i = 0; i < Cc3; ++i) {
            float w = act ? W1[i * C1 + c] : 0.0f;
#pragma unroll
            for (int j = 0; j < K; ++j) acc[j] = fmaf(h[j * Cc3 + i], w, acc[j]);
        }
        if (act) {
            float mv = acc[0];
#pragma unroll
            for (int j = 1; j < K; ++j) mv = fmaxf(mv, acc[j]);
            g[c] = fmaxf(mv, 0.0f);
        }
    }
    __syncthreads();

    // ---- MLP2 on [pooled, ff] ----
    constexpr int Cg = C1 + Cf;
#pragma unroll
    for (int c0 = 0; c0 < C2; c0 += 64) {
        int c = c0 + lane;
        bool act = c < C2;
        float acc = act ? b2[c] : 0.0f;
        for (int i = 0; i < Cg; ++i) {
            float w = act ? W2[i * C2 + c] : 0.0f;
            acc = fmaf(g[i], w, acc);
        }
        if (act) out[qg * C2 + c] = fmaxf(acc, 0.0f);
    }
}

// ---------------------------------------------------------------------------
// f0 = relu(feat @ d0_W + d0_b), 3 -> 32 channels.
// ---------------------------------------------------------------------------
__global__ void f0_kernel(const float* __restrict__ feat, const float* __restrict__ W,
                          const float* __restrict__ bias, float* __restrict__ out)
{
    int t = blockIdx.x * blockDim.x + threadIdx.x;
    int n = t >> 5, c = t & 31;
    const float* f = feat + (size_t)n * 3;
    float acc = bias[c];
    acc = fmaf(f[0], W[c], acc);
    acc = fmaf(f[1], W[32 + c], acc);
    acc = fmaf(f[2], W[64 + c], acc);
    out[t] = fmaxf(acc, 0.0f);
}

// ---------------------------------------------------------------------------

extern "C" void kernel_launch(void* const* d_in, const int* in_sizes, int n_in,
                              void* d_out, int out_size, void* d_ws, size_t ws_size,
                              hipStream_t stream)
{
    const float* pc    = (const float*)d_in[0];
    const float* feat  = (const float*)d_in[1];
    const float* d0_W  = (const float*)d_in[2];
    const float* d0_b  = (const float*)d_in[3];
    const float* d1_W0 = (const float*)d_in[4];
    const float* d1_b0 = (const float*)d_in[5];
    const float* d1_W1 = (const float*)d_in[6];
    const float* d1_b1 = (const float*)d_in[7];
    const float* d2_W0 = (const float*)d_in[8];
    const float* d2_b0 = (const float*)d_in[9];
    const float* d2_W1 = (const float*)d_in[10];
    const float* d2_b1 = (const float*)d_in[11];
    const float* d3_W0 = (const float*)d_in[12];
    const float* d3_b0 = (const float*)d_in[13];
    const float* d3_W1 = (const float*)d_in[14];
    const float* d3_b1 = (const float*)d_in[15];
    const float* d4_W0 = (const float*)d_in[16];
    const float* d4_b0 = (const float*)d_in[17];
    const float* d4_W1 = (const float*)d_in[18];
    const float* d4_b1 = (const float*)d_in[19];
    const float* u4_W1 = (const float*)d_in[20];
    const float* u4_b1 = (const float*)d_in[21];
    const float* u4_W2 = (const float*)d_in[22];
    const float* u4_b2 = (const float*)d_in[23];
    const float* u3_W1 = (const float*)d_in[24];
    const float* u3_b1 = (const float*)d_in[25];
    const float* u3_W2 = (const float*)d_in[26];
    const float* u3_b2 = (const float*)d_in[27];
    const float* u2_W1 = (const float*)d_in[28];
    const float* u2_b1 = (const float*)d_in[29];
    const float* u2_W2 = (const float*)d_in[30];
    const float* u2_b2 = (const float*)d_in[31];
    const float* u1_W1 = (const float*)d_in[32];
    const float* u1_b1 = (const float*)d_in[33];
    const float* u1_W2 = (const float*)d_in[34];
    const float* u1_b2 = (const float*)d_in[35];

    float* out = (float*)d_out;
    float* o_x1 = out + 0;       // 12288
    float* o_x2 = out + 12288;   // 3072
    float* o_x3 = out + 15360;   // 768
    float* o_i1 = out + 16128;   // 4096
    float* o_i2 = out + 20224;   // 1024
    float* o_i3 = out + 21248;   // 256
    float* o_u0 = out + 21504;   // 524288
    float* o_u1 = out + 545792;  // 262144
    float* o_u2 = out + 807936;  // 131072
    float* o_u3 = out + 939008;  // 49152

    float* w = (float*)d_ws;
    float* f0 = w; w += 2 * 8192 * 32;
    float* f1 = w; w += 2 * 2048 * 64;
    float* f2 = w; w += 2 * 512 * 128;
    float* f3 = w; w += 2 * 128 * 192;
    float* f4 = w; w += 2 * 64 * 192;
    float* x4 = w; w += 2 * 64 * 3;

    const int B = 2;

    // one-time setup: LDS caps + second stream + fork/join events
    // (stream/event creation are not stream ops -> legal under capture;
    //  events are DisableTiming as required for capture dependencies)
    static bool init_done = false;
    static hipStream_t s2 = nullptr;
    static hipEvent_t evFork = nullptr, evX1 = nullptr, evX2 = nullptr,
                      evX3 = nullptr, evX4 = nullptr, evJoin = nullptr;
    if (!init_done) {
        (void)hipFuncSetAttribute((const void*)fps_block<256, 32>,
                                  hipFuncAttributeMaxDynamicSharedMemorySize,
                                  8192 * 3 * 4 + 2048 * 4 * 4);          // 131072
        (void)hipFuncSetAttribute((const void*)setconv_full<16, 128, 128, 192>,
                                  hipFuncAttributeMaxDynamicSharedMemorySize,
                                  (4 * 16 + 4 * 16 * 131 + 4 * 16 * 128) * 4); // 66560
        (void)hipFuncSetAttribute((const void*)setconv_full<16, 192, 192, 192>,
                                  hipFuncAttributeMaxDynamicSharedMemorySize,
                                  (4 * 16 + 4 * 16 * 195 + 4 * 16 * 192) * 4); // 99328
        (void)hipStreamCreateWithFlags(&s2, hipStreamNonBlocking);
        (void)hipEventCreateWithFlags(&evFork, hipEventDisableTiming);
        (void)hipEventCreateWithFlags(&evX1, hipEventDisableTiming);
        (void)hipEventCreateWithFlags(&evX2, hipEventDisableTiming);
        (void)hipEventCreateWithFlags(&evX3, hipEventDisableTiming);
        (void)hipEventCreateWithFlags(&evX4, hipEventDisableTiming);
        (void)hipEventCreateWithFlags(&evJoin, hipEventDisableTiming);
        init_done = true;
    }

    // ---- fork: s2 branches off the main stream ----
    (void)hipEventRecord(evFork, stream);
    (void)hipStreamWaitEvent(s2, evFork, 0);

    // f0 on s2, concurrent with fps1
    f0_kernel<<<(2 * 8192 * 32) / 256, 256, 0, s2>>>(feat, d0_W, d0_b, f0);

    // ---- fps chain on main stream ----
    fps_block<256, 32><<<B, 256, 8192 * 3 * 4 + 2048 * 4 * 4, stream>>>(pc, 2048, o_x1, o_i1);
    (void)hipEventRecord(evX1, stream);
    fps_block<256, 8><<<B, 256, 2048 * 3 * 4 + 512 * 4 * 4, stream>>>(o_x1, 512, o_x2, o_i2);
    (void)hipEventRecord(evX2, stream);
    fps_wave<8><<<B, 64, 512 * 3 * 4 + 128 * 4 * 4, stream>>>(o_x2, 128, o_x3, o_i3);
    (void)hipEventRecord(evX3, stream);
    fps_wave<2><<<B, 64, 128 * 3 * 4 + 64 * 4 * 4, stream>>>(o_x3, 64, x4, nullptr);
    (void)hipEventRecord(evX4, stream);

    // ---- feature chain on s2, gated on the fps outputs it needs ----
    (void)hipStreamWaitEvent(s2, evX1, 0);   // o_x1 ready
    setconv_full<16, 32, 32, 64><<<dim3(2048 / 4, B), 256,
        (4 * 16 + 4 * 16 * 35 + 4 * 16 * 32) * 4, s2>>>(
        pc, 8192, f0, o_x1, 2048, d1_W0, d1_b0, d1_W1, d1_b1, f1);
    (void)hipStreamWaitEvent(s2, evX2, 0);   // o_x2 ready
    setconv_full<16, 64, 64, 128><<<dim3(512 / 4, B), 256,
        (4 * 16 + 4 * 16 * 67 + 4 * 16 * 64) * 4, s2>>>(
        o_x1, 2048, f1, o_x2, 512, d2_W0, d2_b0, d2_W1, d2_b1, f2);
    (void)hipStreamWaitEvent(s2, evX3, 0);   // o_x3 ready
    setconv_full<16, 128, 128, 192><<<dim3(128 / 4, B), 256,
        (4 * 16 + 4 * 16 * 131 + 4 * 16 * 128) * 4, s2>>>(
        o_x2, 512, f2, o_x3, 128, d3_W0, d3_b0, d3_W1, d3_b1, f3);
    (void)hipStreamWaitEvent(s2, evX4, 0);   // x4 ready
    setconv_full<16, 192, 192, 192><<<dim3(64 / 4, B), 256,
        (4 * 16 + 4 * 16 * 195 + 4 * 16 * 192) * 4, s2>>>(
        o_x3, 128, f3, x4, 64, d4_W0, d4_b0, d4_W1, d4_b1, f4);

    upconv_full<8, 192, 192, 192, 192><<<dim3(128 / 4, B), 256,
        (4 * 8 + 4 * 8 * 195 + 4 * (192 + 192)) * 4, s2>>>(
        x4, 64, f4, o_x3, 128, f3, u4_W1, u4_b1, u4_W2, u4_b2, o_u3);
    upconv_full<8, 192, 128, 128, 128><<<dim3(512 / 4, B), 256,
        (4 * 8 + 4 * 8 * 195 + 4 * (128 + 128)) * 4, s2>>>(
        o_x3, 128, o_u3, o_x2, 512, f2, u3_W1, u3_b1, u3_W2, u3_b2, o_u2);
    upconv_full<8, 128, 64, 64, 64><<<dim3(2048 / 4, B), 256,
        (4 * 8 + 4 * 8 * 131 + 4 * (64 + 64)) * 4, s2>>>(
        o_x2, 512, o_u2, o_x1, 2048, f1, u2_W1, u2_b1, u2_W2, u2_b2, o_u1);
    upconv_full<8, 64, 32, 32, 32><<<dim3(8192 / 4, B), 256,
        (4 * 8 + 4 * 8 * 67 + 4 * (32 + 32)) * 4, s2>>>(
        o_x1, 2048, o_u1, pc, 8192, f0, u1_W1, u1_b1, u1_W2, u1_b2, o_u0);

    // ---- join: main stream waits for the feature chain ----
    (void)hipEventRecord(evJoin, s2);
    (void)hipStreamWaitEvent(stream, evJoin, 0);
}